// Round 17
// baseline (5841.361 us; speedup 1.0000x reference)
//
#include <hip/hip_runtime.h>
#include <hip/hip_bf16.h>

#define NNODES   32768
#define NGROUPS  512
#define EPG      512
#define ND       (32768l*128)

typedef __attribute__((ext_vector_type(4))) float f32x4;
typedef __attribute__((ext_vector_type(8))) short bf16x8;

__device__ __forceinline__ short f2bf(float x) {
  unsigned u = __float_as_uint(x);
  unsigned r = (u + 0x7FFF + ((u >> 16) & 1)) >> 16;   // RNE
  return (short)r;
}
__device__ __forceinline__ float bf2f(short h) {
  return __uint_as_float(((unsigned)(unsigned short)h) << 16);
}
// 3-term bf16 split: x ~= h + m + l  (covers ~24 mantissa bits)
__device__ __forceinline__ void split3(float x, short* ph, short* pm, short* pl, long idx) {
  short h = f2bf(x); float r1 = x - bf2f(h);
  short m = f2bf(r1); float r2 = r1 - bf2f(m);
  ph[idx] = h; pm[idx] = m; pl[idx] = f2bf(r2);
}

// ---------------------------------------------------------------------------
// h0 = node_features(32768x32) @ W(32x128) + b
__global__ void k_node_enc(const float* __restrict__ nf, const float* __restrict__ w,
                           const float* __restrict__ b, float* __restrict__ h0) {
  int idx = blockIdx.x * 256 + threadIdx.x;
  int row = idx >> 7, col = idx & 127;
  const float* x = nf + row * 32;
  float acc = b[col];
#pragma unroll
  for (int k = 0; k < 32; ++k) acc = fmaf(x[k], w[k * 128 + col], acc);
  h0[idx] = acc;
}

// ---------------------------------------------------------------------------
// Folded weights (fp32):
//  blocks 0..15 : Wfold[16][256] = eew(16x64) @ mw1[256:320,:]
//  block  16    : bfold[256]     = eeb @ mw1[256:320,:] + mb1
//  block  17    : vbias[256]     = mb2 @ nw1[128:256,:]
__global__ void k_prep(const float* __restrict__ eew, const float* __restrict__ eeb,
                       const float* __restrict__ mw1, const float* __restrict__ mb1,
                       const float* __restrict__ mb2, const float* __restrict__ nw1,
                       float* __restrict__ Wfold, float* __restrict__ bfold,
                       float* __restrict__ vbias) {
  const int c = threadIdx.x, b = blockIdx.x;
  if (b < 16) {
    float a = 0.f;
    for (int j = 0; j < 64; ++j) a = fmaf(eew[b * 64 + j], mw1[(256 + j) * 256 + c], a);
    Wfold[b * 256 + c] = a;
  } else if (b == 16) {
    float a = mb1[c];
    for (int j = 0; j < 64; ++j) a = fmaf(eeb[j], mw1[(256 + j) * 256 + c], a);
    bfold[c] = a;
  } else {
    float a = 0.f;
    for (int j = 0; j < 128; ++j) a = fmaf(mb2[j], nw1[(128 + j) * 256 + c], a);
    vbias[c] = a;
  }
}

// ---------------------------------------------------------------------------
// Weight transpose + bf16x3 split: W (>=Kd x C row-major) -> Wt[c][k], k-stride 256
__global__ void k_wsplit3(const float* __restrict__ W, int C, int Kd,
                          short* __restrict__ th, short* __restrict__ tm,
                          short* __restrict__ tl) {
  const int c = blockIdx.x;
  for (int k = threadIdx.x; k < Kd; k += 256) {
    float w = W[(long)k * C + c];
    split3(w, th, tm, tl, c * 256 + k);
  }
}

// ---------------------------------------------------------------------------
// Deterministic CSR per group: edges stably sorted by to-node.
__global__ void k_csr(const int* __restrict__ from_idx, const int* __restrict__ to_idx,
                      const float* __restrict__ ef,
                      int* __restrict__ csr_f, int* __restrict__ rp_g,
                      float* __restrict__ efp, int* __restrict__ deg) {
  __shared__ int cnt[64], rps[65];
  __shared__ int tls[EPG], fls[EPG];
  __shared__ short ord[EPG];
  const int g = blockIdx.x, tid = threadIdx.x;
  const int be = g * EPG, bn = g * 64;
  if (tid < 64) cnt[tid] = 0;
  __syncthreads();
  for (int e = tid; e < EPG; e += 256) {
    int t = to_idx[be + e] - bn;
    tls[e] = t;
    fls[e] = from_idx[be + e] - bn;
    atomicAdd(&cnt[t], 1);
  }
  __syncthreads();
  if (tid == 0) {
    int s = 0;
    for (int i = 0; i < 64; ++i) { rps[i] = s; s += cnt[i]; }
    rps[64] = s;
  }
  __syncthreads();
  if (tid < 64) {
    int pos = rps[tid];
    for (int e = 0; e < EPG; ++e)
      if (tls[e] == tid) ord[pos++] = (short)e;
  }
  __syncthreads();
  for (int ec = tid; ec < EPG; ec += 256) {
    const int eo = ord[ec];
    csr_f[be + ec] = fls[eo];
    const float4* src = (const float4*)&ef[(long)(be + eo) * 16];
    float4* dst = (float4*)&efp[(long)(be + ec) * 16];
    dst[0] = src[0]; dst[1] = src[1]; dst[2] = src[2]; dst[3] = src[3];
  }
  if (tid < 65) rp_g[g * 65 + tid] = rps[tid];
  if (tid < 64) deg[bn + tid] = cnt[tid];
}

// ---------------------------------------------------------------------------
// MFMA bf16x3 2-layer MLP. X = [x0 | x1].
// RPX0: x0 read from pre-split planes. WPOUT: output written as bf16x3 planes.
// AGG: x1 is ag (N x 256); a pre-phase computes agg = ag @ mw2 via MFMA
//      (two-chain, bit-identical to the former k_aggm) and stages it as
//      bf16x3 into cols 128..255 of the staging buffer.
template<int KTOT, bool DEG, bool RPX0, bool WPOUT, bool AGG>
__global__ __launch_bounds__(256, 3)
void k_mlp2m(const float* __restrict__ x0,
             const short* __restrict__ x0h, const short* __restrict__ x0m,
             const short* __restrict__ x0l,
             const float* __restrict__ x1,
             const short* __restrict__ A2h, const short* __restrict__ A2m,
             const short* __restrict__ A2l,
             const short* __restrict__ W1h, const short* __restrict__ W1m,
             const short* __restrict__ W1l,
             const float* __restrict__ b1, const int* __restrict__ deg,
             const float* __restrict__ vbias,
             const short* __restrict__ W2h, const short* __restrict__ W2m,
             const short* __restrict__ W2l,
             const float* __restrict__ b2,
             float* __restrict__ out,
             short* __restrict__ outh, short* __restrict__ outm,
             short* __restrict__ outl) {
  __shared__ short xh[32 * 264];
  __shared__ short xm[32 * 264];
  __shared__ short xl[32 * 264];
  __shared__ int degs[32];
  const int tid = threadIdx.x;
  const long row0 = (long)blockIdx.x * 32;

  const int lane = tid & 63, wid = tid >> 6;
  const int lr = lane & 15;
  const int lk = (lane >> 4) * 8;
  const int rsub = (lane >> 4) * 4;

  if constexpr (AGG) {
    // pre-phase: agg(32x128) = ag(32x256) @ mw2, two accumulation chains
    for (int i = tid; i < 2048; i += 256) {
      const int r = i >> 6, q = i & 63;
      float4 v = *(const float4*)&x1[(row0 + r) * 256 + q * 4];
      const int base = r * 264 + q * 4;
      split3(v.x, xh, xm, xl, base + 0);
      split3(v.y, xh, xm, xl, base + 1);
      split3(v.z, xh, xm, xl, base + 2);
      split3(v.w, xh, xm, xl, base + 3);
    }
    __syncthreads();

    f32x4 s0[2][2], s1[2][2];
#pragma unroll
    for (int fc = 0; fc < 2; ++fc)
#pragma unroll
      for (int fr = 0; fr < 2; ++fr) { s0[fr][fc] = {0.f,0.f,0.f,0.f}; s1[fr][fc] = {0.f,0.f,0.f,0.f}; }

#pragma unroll 2
    for (int ks = 0; ks < 4; ++ks) {          // K half 0: 0..127
      const int k0 = ks * 32 + lk;
      bf16x8 ah[2], am[2], al[2];
#pragma unroll
      for (int fr = 0; fr < 2; ++fr) {
        const int ab = (fr * 16 + lr) * 264 + k0;
        ah[fr] = *(const bf16x8*)&xh[ab];
        am[fr] = *(const bf16x8*)&xm[ab];
        al[fr] = *(const bf16x8*)&xl[ab];
      }
#pragma unroll
      for (int fc = 0; fc < 2; ++fc) {
        const long wrow = (long)(wid * 32 + fc * 16 + lr) * 256 + k0;
        const bf16x8 bh = *(const bf16x8*)&A2h[wrow];
        const bf16x8 bm = *(const bf16x8*)&A2m[wrow];
        const bf16x8 bl = *(const bf16x8*)&A2l[wrow];
#pragma unroll
        for (int fr = 0; fr < 2; ++fr) {
          s0[fr][fc] = __builtin_amdgcn_mfma_f32_16x16x32_bf16(ah[fr], bh, s0[fr][fc], 0, 0, 0);
          s0[fr][fc] = __builtin_amdgcn_mfma_f32_16x16x32_bf16(ah[fr], bm, s0[fr][fc], 0, 0, 0);
          s0[fr][fc] = __builtin_amdgcn_mfma_f32_16x16x32_bf16(am[fr], bh, s0[fr][fc], 0, 0, 0);
          s0[fr][fc] = __builtin_amdgcn_mfma_f32_16x16x32_bf16(ah[fr], bl, s0[fr][fc], 0, 0, 0);
          s0[fr][fc] = __builtin_amdgcn_mfma_f32_16x16x32_bf16(am[fr], bm, s0[fr][fc], 0, 0, 0);
          s0[fr][fc] = __builtin_amdgcn_mfma_f32_16x16x32_bf16(al[fr], bh, s0[fr][fc], 0, 0, 0);
        }
      }
    }
#pragma unroll 2
    for (int ks = 4; ks < 8; ++ks) {          // K half 1: 128..255
      const int k0 = ks * 32 + lk;
      bf16x8 ah[2], am[2], al[2];
#pragma unroll
      for (int fr = 0; fr < 2; ++fr) {
        const int ab = (fr * 16 + lr) * 264 + k0;
        ah[fr] = *(const bf16x8*)&xh[ab];
        am[fr] = *(const bf16x8*)&xm[ab];
        al[fr] = *(const bf16x8*)&xl[ab];
      }
#pragma unroll
      for (int fc = 0; fc < 2; ++fc) {
        const long wrow = (long)(wid * 32 + fc * 16 + lr) * 256 + k0;
        const bf16x8 bh = *(const bf16x8*)&A2h[wrow];
        const bf16x8 bm = *(const bf16x8*)&A2m[wrow];
        const bf16x8 bl = *(const bf16x8*)&A2l[wrow];
#pragma unroll
        for (int fr = 0; fr < 2; ++fr) {
          s1[fr][fc] = __builtin_amdgcn_mfma_f32_16x16x32_bf16(ah[fr], bh, s1[fr][fc], 0, 0, 0);
          s1[fr][fc] = __builtin_amdgcn_mfma_f32_16x16x32_bf16(ah[fr], bm, s1[fr][fc], 0, 0, 0);
          s1[fr][fc] = __builtin_amdgcn_mfma_f32_16x16x32_bf16(am[fr], bh, s1[fr][fc], 0, 0, 0);
          s1[fr][fc] = __builtin_amdgcn_mfma_f32_16x16x32_bf16(ah[fr], bl, s1[fr][fc], 0, 0, 0);
          s1[fr][fc] = __builtin_amdgcn_mfma_f32_16x16x32_bf16(am[fr], bm, s1[fr][fc], 0, 0, 0);
          s1[fr][fc] = __builtin_amdgcn_mfma_f32_16x16x32_bf16(al[fr], bh, s1[fr][fc], 0, 0, 0);
        }
      }
    }
    __syncthreads();   // all ag reads done before staging overwrite

    // split3(agg) into cols 128..255 (same value as old global round-trip)
#pragma unroll
    for (int fr = 0; fr < 2; ++fr)
#pragma unroll
      for (int fc = 0; fc < 2; ++fc) {
        const int col = wid * 32 + fc * 16 + lr;
#pragma unroll
        for (int r = 0; r < 4; ++r) {
          const int row = fr * 16 + rsub + r;
          split3(s0[fr][fc][r] + s1[fr][fc][r], xh, xm, xl, row * 264 + 128 + col);
        }
      }
  }

  if constexpr (RPX0) {
    for (int i = tid; i < 32 * 16; i += 256) {
      const int r = i >> 4, q = i & 15;
      const long gb = (row0 + r) * 128 + q * 8;
      const int lb = r * 264 + q * 8;
      *(bf16x8*)&xh[lb] = *(const bf16x8*)&x0h[gb];
      *(bf16x8*)&xm[lb] = *(const bf16x8*)&x0m[gb];
      *(bf16x8*)&xl[lb] = *(const bf16x8*)&x0l[gb];
    }
  } else {
    for (int i = tid; i < 32 * 32; i += 256) {
      const int r = i >> 5, q = i & 31;
      float4 v = *(const float4*)&x0[(row0 + r) * 128 + q * 4];
      const int base = r * 264 + q * 4;
      split3(v.x, xh, xm, xl, base + 0);
      split3(v.y, xh, xm, xl, base + 1);
      split3(v.z, xh, xm, xl, base + 2);
      split3(v.w, xh, xm, xl, base + 3);
    }
  }
  if constexpr (KTOT == 256 && !AGG) {
    for (int i = tid; i < 32 * 32; i += 256) {
      const int r = i >> 5, q = i & 31;
      float4 v = *(const float4*)&x1[(row0 + r) * 128 + q * 4];
      const int base = r * 264 + 128 + q * 4;
      split3(v.x, xh, xm, xl, base + 0);
      split3(v.y, xh, xm, xl, base + 1);
      split3(v.z, xh, xm, xl, base + 2);
      split3(v.w, xh, xm, xl, base + 3);
    }
  }
  if constexpr (DEG) { if (tid < 32) degs[tid] = deg[row0 + tid]; }
  __syncthreads();

  // ---- layer 1: 32 x 256, wave cols [wid*64, wid*64+64) ----
  f32x4 acc[2][4];
#pragma unroll
  for (int fc = 0; fc < 4; ++fc) {
    const int col = wid * 64 + fc * 16 + lr;
    const float bv = b1[col];
#pragma unroll
    for (int fr = 0; fr < 2; ++fr) acc[fr][fc] = {bv, bv, bv, bv};
    if constexpr (DEG) {
      const float vb = vbias[col];
#pragma unroll
      for (int fr = 0; fr < 2; ++fr)
#pragma unroll
        for (int r = 0; r < 4; ++r)
          acc[fr][fc][r] += (float)degs[fr * 16 + rsub + r] * vb;
    }
  }

#pragma unroll 2
  for (int ks = 0; ks < KTOT / 32; ++ks) {
    const int k0 = ks * 32 + lk;
    bf16x8 ah[2], am[2], al[2];
#pragma unroll
    for (int fr = 0; fr < 2; ++fr) {
      const int ab = (fr * 16 + lr) * 264 + k0;
      ah[fr] = *(const bf16x8*)&xh[ab];
      am[fr] = *(const bf16x8*)&xm[ab];
      al[fr] = *(const bf16x8*)&xl[ab];
    }
#pragma unroll
    for (int fc = 0; fc < 4; ++fc) {
      const long wrow = (long)(wid * 64 + fc * 16 + lr) * 256 + k0;
      const bf16x8 bh = *(const bf16x8*)&W1h[wrow];
      const bf16x8 bm = *(const bf16x8*)&W1m[wrow];
      const bf16x8 bl = *(const bf16x8*)&W1l[wrow];
#pragma unroll
      for (int fr = 0; fr < 2; ++fr) {
        acc[fr][fc] = __builtin_amdgcn_mfma_f32_16x16x32_bf16(ah[fr], bh, acc[fr][fc], 0, 0, 0);
        acc[fr][fc] = __builtin_amdgcn_mfma_f32_16x16x32_bf16(ah[fr], bm, acc[fr][fc], 0, 0, 0);
        acc[fr][fc] = __builtin_amdgcn_mfma_f32_16x16x32_bf16(am[fr], bh, acc[fr][fc], 0, 0, 0);
        acc[fr][fc] = __builtin_amdgcn_mfma_f32_16x16x32_bf16(ah[fr], bl, acc[fr][fc], 0, 0, 0);
        acc[fr][fc] = __builtin_amdgcn_mfma_f32_16x16x32_bf16(am[fr], bm, acc[fr][fc], 0, 0, 0);
        acc[fr][fc] = __builtin_amdgcn_mfma_f32_16x16x32_bf16(al[fr], bh, acc[fr][fc], 0, 0, 0);
      }
    }
  }
  __syncthreads();

  // relu + split3 + store hidden to LDS [row][hcol]
#pragma unroll
  for (int fr = 0; fr < 2; ++fr)
#pragma unroll
    for (int fc = 0; fc < 4; ++fc) {
      const int col = wid * 64 + fc * 16 + lr;
#pragma unroll
      for (int r = 0; r < 4; ++r) {
        const int row = fr * 16 + rsub + r;
        float v = fmaxf(acc[fr][fc][r], 0.f);
        split3(v, xh, xm, xl, row * 264 + col);
      }
    }
  __syncthreads();

  // ---- layer 2: 32 x 128, wave cols [wid*32, wid*32+32) ----
  f32x4 acc2[2][2];
#pragma unroll
  for (int fc = 0; fc < 2; ++fc) {
    const float bv = b2[wid * 32 + fc * 16 + lr];
#pragma unroll
    for (int fr = 0; fr < 2; ++fr) acc2[fr][fc] = {bv, bv, bv, bv};
  }
#pragma unroll 2
  for (int ks = 0; ks < 8; ++ks) {
    const int k0 = ks * 32 + lk;
    bf16x8 ah[2], am[2], al[2];
#pragma unroll
    for (int fr = 0; fr < 2; ++fr) {
      const int ab = (fr * 16 + lr) * 264 + k0;
      ah[fr] = *(const bf16x8*)&xh[ab];
      am[fr] = *(const bf16x8*)&xm[ab];
      al[fr] = *(const bf16x8*)&xl[ab];
    }
#pragma unroll
    for (int fc = 0; fc < 2; ++fc) {
      const long wrow = (long)(wid * 32 + fc * 16 + lr) * 256 + k0;
      const bf16x8 bh = *(const bf16x8*)&W2h[wrow];
      const bf16x8 bm = *(const bf16x8*)&W2m[wrow];
      const bf16x8 bl = *(const bf16x8*)&W2l[wrow];
#pragma unroll
      for (int fr = 0; fr < 2; ++fr) {
        acc2[fr][fc] = __builtin_amdgcn_mfma_f32_16x16x32_bf16(ah[fr], bh, acc2[fr][fc], 0, 0, 0);
        acc2[fr][fc] = __builtin_amdgcn_mfma_f32_16x16x32_bf16(ah[fr], bm, acc2[fr][fc], 0, 0, 0);
        acc2[fr][fc] = __builtin_amdgcn_mfma_f32_16x16x32_bf16(am[fr], bh, acc2[fr][fc], 0, 0, 0);
        acc2[fr][fc] = __builtin_amdgcn_mfma_f32_16x16x32_bf16(ah[fr], bl, acc2[fr][fc], 0, 0, 0);
        acc2[fr][fc] = __builtin_amdgcn_mfma_f32_16x16x32_bf16(am[fr], bm, acc2[fr][fc], 0, 0, 0);
        acc2[fr][fc] = __builtin_amdgcn_mfma_f32_16x16x32_bf16(al[fr], bh, acc2[fr][fc], 0, 0, 0);
      }
    }
  }
#pragma unroll
  for (int fr = 0; fr < 2; ++fr)
#pragma unroll
    for (int fc = 0; fc < 2; ++fc) {
      const int col = wid * 32 + fc * 16 + lr;
#pragma unroll
      for (int r = 0; r < 4; ++r) {
        const long gi = (row0 + fr * 16 + rsub + r) * 128 + col;
        if constexpr (WPOUT) {
          split3(acc2[fr][fc][r], outh, outm, outl, gi);
        } else {
          out[gi] = acc2[fr][fc][r];
        }
      }
    }
}

// ---------------------------------------------------------------------------
// Edge kernel, phases a+b. grid (512, 4): block = (group, 64-col block).
// phase a: cA/cB = comb_planes @ mw1t[cb] (MFMA) -> LDS.
// phase b: CSR edge loop (3-edge ILP) -> hidden-sum written to global ag (N x 256).
// 4 blocks/CU: LDS 36.3KB*4 = 145KB <= 160; measured VGPR demand 84 <= 128 cap.
__global__ __launch_bounds__(256, 4)
void k_edgeb(const short* __restrict__ chp, const short* __restrict__ cmp,
             const short* __restrict__ clp,
             const float* __restrict__ efp,
             const short* __restrict__ m1h, const short* __restrict__ m1m,
             const short* __restrict__ m1l,
             const float* __restrict__ Wfold, const float* __restrict__ bfold,
             const int* __restrict__ csr_f, const int* __restrict__ rp_g,
             float* __restrict__ ag) {
  __shared__ __align__(16) float cAB[2 * 64 * 68];   // cA | cB
  __shared__ short fl[EPG];
  __shared__ int rp[65];
  float* cA = cAB;
  float* cB = cAB + 64 * 68;

  const int tid = threadIdx.x;
  const int g = blockIdx.x, cb = blockIdx.y;
  const int be = g * EPG, bn = g * 64;
  const int col0 = cb * 64;

  for (int i = tid; i < EPG; i += 256) fl[i] = (short)csr_f[be + i];
  if (tid < 65) rp[tid] = rp_g[g * 65 + tid];

  const int lane = tid & 63, wid = tid >> 6;
  const int lr = lane & 15;
  const int lk = (lane >> 4) * 8;
  const int rsub = (lane >> 4) * 4;
  const int ng = tid >> 4, cg = tid & 15;
  const int n0 = ng * 4, cq = cg * 4;

  // phase a: waves 0,1 -> cA (mw1 k 0..127); waves 2,3 -> cB (k 128..255).
  {
    const int isB = wid >> 1;
    const int cw = (wid & 1) * 32;
    const int wkof = isB * 128;
    float* dstC = isB ? cB : cA;
#pragma unroll 1
    for (int hf = 0; hf < 2; ++hf) {
      f32x4 c[2][2];
#pragma unroll
      for (int fr = 0; fr < 2; ++fr)
#pragma unroll
        for (int fc = 0; fc < 2; ++fc) c[fr][fc] = {0.f, 0.f, 0.f, 0.f};
      for (int ks = 0; ks < 4; ++ks) {
        const int k0 = ks * 32 + lk;
        bf16x8 ah[2], am[2], al[2];
#pragma unroll
        for (int fr = 0; fr < 2; ++fr) {
          const long ga = (long)(bn + (hf * 2 + fr) * 16 + lr) * 128 + k0;
          ah[fr] = *(const bf16x8*)&chp[ga];
          am[fr] = *(const bf16x8*)&cmp[ga];
          al[fr] = *(const bf16x8*)&clp[ga];
        }
#pragma unroll
        for (int fc = 0; fc < 2; ++fc) {
          const long wrow = (long)(col0 + cw + fc * 16 + lr) * 256 + wkof + k0;
          const bf16x8 bh = *(const bf16x8*)&m1h[wrow];
          const bf16x8 bm = *(const bf16x8*)&m1m[wrow];
          const bf16x8 bl = *(const bf16x8*)&m1l[wrow];
#pragma unroll
          for (int fr = 0; fr < 2; ++fr) {
            c[fr][fc] = __builtin_amdgcn_mfma_f32_16x16x32_bf16(ah[fr], bh, c[fr][fc], 0, 0, 0);
            c[fr][fc] = __builtin_amdgcn_mfma_f32_16x16x32_bf16(ah[fr], bm, c[fr][fc], 0, 0, 0);
            c[fr][fc] = __builtin_amdgcn_mfma_f32_16x16x32_bf16(am[fr], bh, c[fr][fc], 0, 0, 0);
            c[fr][fc] = __builtin_amdgcn_mfma_f32_16x16x32_bf16(ah[fr], bl, c[fr][fc], 0, 0, 0);
            c[fr][fc] = __builtin_amdgcn_mfma_f32_16x16x32_bf16(am[fr], bm, c[fr][fc], 0, 0, 0);
            c[fr][fc] = __builtin_amdgcn_mfma_f32_16x16x32_bf16(al[fr], bh, c[fr][fc], 0, 0, 0);
          }
        }
      }
#pragma unroll
      for (int fr = 0; fr < 2; ++fr)
#pragma unroll
        for (int fc = 0; fc < 2; ++fc) {
          const int col = cw + fc * 16 + lr;
#pragma unroll
          for (int r = 0; r < 4; ++r)
            dstC[((hf * 2 + fr) * 16 + rsub + r) * 68 + col] = c[fr][fc][r];
        }
    }
  }
  float4 Wf[16];
#pragma unroll
  for (int k = 0; k < 16; ++k) Wf[k] = *(const float4*)&Wfold[k * 256 + col0 + cq];
  const float4 bf = *(const float4*)&bfold[col0 + cq];
  __syncthreads();   // cA/cB + fl/rp visible

  // phase b: edge phase (fp32 CSR, atomic-free, 3-edge ILP) -> global ag
#pragma unroll
  for (int i = 0; i < 4; ++i) {
    const int n = n0 + i;
    const float4 cBn = *(const float4*)&cB[n * 68 + cq];
    const int eEnd = rp[n + 1];
    float4 a0 = make_float4(0.f, 0.f, 0.f, 0.f);
    float4 a1 = make_float4(0.f, 0.f, 0.f, 0.f);
    float4 a2 = make_float4(0.f, 0.f, 0.f, 0.f);
    int e = rp[n];
    for (; e + 2 < eEnd; e += 3) {
      const int f0 = fl[e], f1 = fl[e + 1], f2 = fl[e + 2];
      const float* er0 = efp + (long)(be + e) * 16;
      const float* er1 = efp + (long)(be + e + 1) * 16;
      const float* er2 = efp + (long)(be + e + 2) * 16;
      float4 ea[4], eb[4], ec[4];
#pragma unroll
      for (int kq = 0; kq < 4; ++kq) {
        ea[kq] = ((const float4*)er0)[kq];
        eb[kq] = ((const float4*)er1)[kq];
        ec[kq] = ((const float4*)er2)[kq];
      }
      float4 h0 = bf, h1 = bf, h2 = bf;
#pragma unroll
      for (int kq = 0; kq < 4; ++kq) {
        const float ev0[4] = {ea[kq].x, ea[kq].y, ea[kq].z, ea[kq].w};
        const float ev1[4] = {eb[kq].x, eb[kq].y, eb[kq].z, eb[kq].w};
        const float ev2[4] = {ec[kq].x, ec[kq].y, ec[kq].z, ec[kq].w};
#pragma unroll
        for (int s = 0; s < 4; ++s) {
          const float4 w = Wf[kq * 4 + s];
          h0.x = fmaf(ev0[s], w.x, h0.x); h0.y = fmaf(ev0[s], w.y, h0.y);
          h0.z = fmaf(ev0[s], w.z, h0.z); h0.w = fmaf(ev0[s], w.w, h0.w);
          h1.x = fmaf(ev1[s], w.x, h1.x); h1.y = fmaf(ev1[s], w.y, h1.y);
          h1.z = fmaf(ev1[s], w.z, h1.z); h1.w = fmaf(ev1[s], w.w, h1.w);
          h2.x = fmaf(ev2[s], w.x, h2.x); h2.y = fmaf(ev2[s], w.y, h2.y);
          h2.z = fmaf(ev2[s], w.z, h2.z); h2.w = fmaf(ev2[s], w.w, h2.w);
        }
      }
      const float4 va0 = *(const float4*)&cA[f0 * 68 + cq];
      const float4 va1 = *(const float4*)&cA[f1 * 68 + cq];
      const float4 va2 = *(const float4*)&cA[f2 * 68 + cq];
      a0.x += fmaxf(h0.x + va0.x + cBn.x, 0.f);
      a0.y += fmaxf(h0.y + va0.y + cBn.y, 0.f);
      a0.z += fmaxf(h0.z + va0.z + cBn.z, 0.f);
      a0.w += fmaxf(h0.w + va0.w + cBn.w, 0.f);
      a1.x += fmaxf(h1.x + va1.x + cBn.x, 0.f);
      a1.y += fmaxf(h1.y + va1.y + cBn.y, 0.f);
      a1.z += fmaxf(h1.z + va1.z + cBn.z, 0.f);
      a1.w += fmaxf(h1.w + va1.w + cBn.w, 0.f);
      a2.x += fmaxf(h2.x + va2.x + cBn.x, 0.f);
      a2.y += fmaxf(h2.y + va2.y + cBn.y, 0.f);
      a2.z += fmaxf(h2.z + va2.z + cBn.z, 0.f);
      a2.w += fmaxf(h2.w + va2.w + cBn.w, 0.f);
    }
    for (; e < eEnd; ++e) {   // tail (0..2 edges)
      const int f = fl[e];
      const float* er = efp + (long)(be + e) * 16;
      float4 h = bf;
#pragma unroll
      for (int kq = 0; kq < 4; ++kq) {
        const float4 e4 = ((const float4*)er)[kq];
        const float ev[4] = {e4.x, e4.y, e4.z, e4.w};
#pragma unroll
        for (int s = 0; s < 4; ++s) {
          const float4 w = Wf[kq * 4 + s];
          h.x = fmaf(ev[s], w.x, h.x); h.y = fmaf(ev[s], w.y, h.y);
          h.z = fmaf(ev[s], w.z, h.z); h.w = fmaf(ev[s], w.w, h.w);
        }
      }
      const float4 va = *(const float4*)&cA[f * 68 + cq];
      a0.x += fmaxf(h.x + va.x + cBn.x, 0.f);
      a0.y += fmaxf(h.y + va.y + cBn.y, 0.f);
      a0.z += fmaxf(h.z + va.z + cBn.z, 0.f);
      a0.w += fmaxf(h.w + va.w + cBn.w, 0.f);
    }
    a0.x += a1.x; a0.y += a1.y; a0.z += a1.z; a0.w += a1.w;
    a0.x += a2.x; a0.y += a2.y; a0.z += a2.z; a0.w += a2.w;
    *(float4*)&ag[(long)(bn + n) * 256 + col0 + cq] = a0;
  }
}

// ---------------------------------------------------------------------------
__global__ void k_tfeat(const float* __restrict__ x,
                        const float* __restrict__ t1w, const float* __restrict__ t1b,
                        const float* __restrict__ t2w, const float* __restrict__ t2b,
                        float* __restrict__ tf) {
  __shared__ float xs[4][128];
  __shared__ float ys[4][64];
  const int tid = threadIdx.x;
  const long row0 = (long)blockIdx.x * 4;
  for (int i = tid; i < 512; i += 256)
    xs[i >> 7][i & 127] = x[(row0 + (i >> 7)) * 128 + (i & 127)];
  __syncthreads();
  const int r = tid >> 6, c = tid & 63;
  float acc = t1b[c];
#pragma unroll 4
  for (int k = 0; k < 128; ++k) acc = fmaf(xs[r][k], t1w[k * 64 + c], acc);
  ys[r][c] = fmaxf(acc, 0.f);
  __syncthreads();
  float a2 = t2b[c];
#pragma unroll 4
  for (int k = 0; k < 64; ++k) a2 = fmaf(ys[r][k], t2w[k * 64 + c], a2);
  tf[(row0 + r) * 64 + c] = a2;
}

// ---------------------------------------------------------------------------
__global__ void k_sim(const float* __restrict__ tf, float* __restrict__ sim) {
  const int b = blockIdx.x, tid = threadIdx.x;
  __shared__ float tq[64][65];
  __shared__ float tcs[64][65];
  for (int i = tid; i < 4096; i += 256) {
    tq[i >> 6][i & 63]  = tf[(long)b * 8192 + i];
    tcs[i >> 6][i & 63] = tf[(long)b * 8192 + 4096 + i];
  }
  __syncthreads();
  const int m = tid >> 2, j0 = (tid & 3) * 16;
#pragma unroll
  for (int j = 0; j < 16; ++j) {
    float a = 0.f;
#pragma unroll 4
    for (int k = 0; k < 64; ++k) a = fmaf(tq[m][k], tcs[j0 + j][k], a);
    sim[(long)b * 4096 + m * 64 + j0 + j] = a;
  }
}

// ---------------------------------------------------------------------------
__global__ void k_sink(float* __restrict__ sim, float* __restrict__ outp) {
  const int b = blockIdx.x, tid = threadIdx.x;
  __shared__ float la[64][65];
  const float C = 14.426950408889634f;   // 10 / ln(2)
  for (int i = tid; i < 4096; i += 256)
    la[i >> 6][i & 63] = sim[(long)b * 4096 + i] * C;
  __syncthreads();
  const int r4 = tid >> 2, l4 = tid & 3;
  for (int it = 0; it < 20; ++it) {
    {
      float m = -3.4e38f;
#pragma unroll
      for (int i = 0; i < 16; ++i) m = fmaxf(m, la[r4][l4 + 4 * i]);
      m = fmaxf(m, __shfl_xor(m, 1)); m = fmaxf(m, __shfl_xor(m, 2));
      float s = 0.f;
#pragma unroll
      for (int i = 0; i < 16; ++i) s += exp2f(la[r4][l4 + 4 * i] - m);
      s += __shfl_xor(s, 1); s += __shfl_xor(s, 2);
      const float lse = m + log2f(s);
#pragma unroll
      for (int i = 0; i < 16; ++i) la[r4][l4 + 4 * i] -= lse;
    }
    __syncthreads();
    {
      float m = -3.4e38f;
#pragma unroll
      for (int i = 0; i < 16; ++i) m = fmaxf(m, la[l4 + 4 * i][r4]);
      m = fmaxf(m, __shfl_xor(m, 1)); m = fmaxf(m, __shfl_xor(m, 2));
      float s = 0.f;
#pragma unroll
      for (int i = 0; i < 16; ++i) s += exp2f(la[l4 + 4 * i][r4] - m);
      s += __shfl_xor(s, 1); s += __shfl_xor(s, 2);
      const float lse = m + log2f(s);
#pragma unroll
      for (int i = 0; i < 16; ++i) la[l4 + 4 * i][r4] -= lse;
    }
    __syncthreads();
  }
  for (int i = tid; i < 4096; i += 256) {
    const float v = exp2f(la[i >> 6][i & 63]);
    outp[(long)b * 4096 + i] = v;
    sim[(long)b * 4096 + i] = v;
  }
}

// ---------------------------------------------------------------------------
__global__ void k_mix(const float* __restrict__ plan, const float* __restrict__ src,
                      float* __restrict__ dst) {
  const int b = blockIdx.x, tid = threadIdx.x;
  __shared__ float pl[64][65];
  __shared__ float qs[64][128];
  __shared__ float cs[64][128];
  const long qbase = (long)(2 * b) * 64, cbase = qbase + 64;
  for (int i = tid; i < 4096; i += 256) pl[i >> 6][i & 63] = plan[(long)b * 4096 + i];
  for (int i = tid; i < 8192; i += 256) {
    qs[i >> 7][i & 127] = src[qbase * 128 + i];
    cs[i >> 7][i & 127] = src[cbase * 128 + i];
  }
  __syncthreads();
  const int d = tid & 127, m0 = (tid >> 7) * 32;
  for (int m = m0; m < m0 + 32; ++m) {
    float a = 0.f;
#pragma unroll 4
    for (int j = 0; j < 64; ++j) a = fmaf(pl[m][j], cs[j][d], a);
    dst[(qbase + m) * 128 + d] = a;
  }
  for (int j = m0; j < m0 + 32; ++j) {
    float a = 0.f;
#pragma unroll 4
    for (int m = 0; m < 64; ++m) a = fmaf(pl[m][j], qs[m][d], a);
    dst[(cbase + j) * 128 + d] = a;
  }
}

// ---------------------------------------------------------------------------
extern "C" void kernel_launch(void* const* d_in, const int* in_sizes, int n_in,
                              void* d_out, int out_size, void* d_ws, size_t ws_size,
                              hipStream_t stream) {
  const float* nf  = (const float*)d_in[0];
  const float* ef  = (const float*)d_in[1];
  const int* from_idx = (const int*)d_in[2];
  const int* to_idx   = (const int*)d_in[3];
  const float* new_w = (const float*)d_in[4];
  const float* new_b = (const float*)d_in[5];
  const float* eew = (const float*)d_in[6];
  const float* eeb = (const float*)d_in[7];
  const float* mw1 = (const float*)d_in[8];
  const float* mb1 = (const float*)d_in[9];
  const float* mw2 = (const float*)d_in[10];
  const float* mb2 = (const float*)d_in[11];
  const float* nw1 = (const float*)d_in[12];
  const float* nb1 = (const float*)d_in[13];
  const float* nw2 = (const float*)d_in[14];
  const float* nb2 = (const float*)d_in[15];
  const float* cw1 = (const float*)d_in[16];
  const float* cb1 = (const float*)d_in[17];
  const float* cw2 = (const float*)d_in[18];
  const float* cb2 = (const float*)d_in[19];
  const float* t1w = (const float*)d_in[20];
  const float* t1b = (const float*)d_in[21];
  const float* t2w = (const float*)d_in[22];
  const float* t2b = (const float*)d_in[23];

  float* W = (float*)d_ws;
  float* h0     = W;                       // ND
  float* aggM0  = h0 + ND;                 // ND (tf/sim alias here)
  float* ag     = aggM0 + ND;              // 2*ND  (N x 256 hidden sums)
  float* parts  = ag + 2 * ND;             // 5*ND
  float* efp    = parts + 5 * ND;          // 262144*16
  float* Wfold  = efp + 262144l * 16;      // 4096
  float* bfold  = Wfold + 4096;            // 256
  float* vbias  = bfold + 256;             // 256
  int*   deg    = (int*)(vbias + 256);     // 32768
  int*   csr_f  = deg + 32768;             // 262144
  int*   rp_g   = csr_f + 262144;          // 512*65 = 33280
  short* cw1t_h = (short*)(rp_g + 33280);  // 65536 shorts per plane
  short* cw1t_m = cw1t_h + 65536;
  short* cw1t_l = cw1t_m + 65536;
  short* nw1t_h = cw1t_l + 65536;
  short* nw1t_m = nw1t_h + 65536;
  short* nw1t_l = nw1t_m + 65536;
  short* cw2t_h = nw1t_l + 65536;          // 32768 each
  short* cw2t_m = cw2t_h + 32768;
  short* cw2t_l = cw2t_m + 32768;
  short* nw2t_h = cw2t_l + 32768;
  short* nw2t_m = nw2t_h + 32768;
  short* nw2t_l = nw2t_m + 32768;
  short* m1t_h  = nw2t_l + 32768;          // mw1[0:256] -> 65536 each
  short* m1t_m  = m1t_h + 65536;
  short* m1t_l  = m1t_m + 65536;
  short* m2t_h  = m1t_l + 65536;           // mw2 -> 32768 each
  short* m2t_m  = m2t_h + 32768;
  short* m2t_l  = m2t_m + 32768;
  short* chp    = m2t_l + 32768;           // comb planes: 32768*128 shorts each
  short* cmp    = chp + 32768l * 128;
  short* clp    = cmp + 32768l * 128;
  float* tf     = aggM0;                   // 32768*64
  float* sim    = aggM0 + 2097152;         // 256*4096
  float* outp   = (float*)d_out;

  k_prep<<<18, 256, 0, stream>>>(eew, eeb, mw1, mb1, mb2, nw1, Wfold, bfold, vbias);
  k_csr<<<512, 256, 0, stream>>>(from_idx, to_idx, ef, csr_f, rp_g, efp, deg);
  k_wsplit3<<<256, 256, 0, stream>>>(cw1, 256, 256, cw1t_h, cw1t_m, cw1t_l);
  k_wsplit3<<<256, 256, 0, stream>>>(nw1, 256, 256, nw1t_h, nw1t_m, nw1t_l);
  k_wsplit3<<<128, 256, 0, stream>>>(cw2, 128, 256, cw2t_h, cw2t_m, cw2t_l);
  k_wsplit3<<<128, 256, 0, stream>>>(nw2, 128, 256, nw2t_h, nw2t_m, nw2t_l);
  k_wsplit3<<<256, 256, 0, stream>>>(mw1, 256, 256, m1t_h, m1t_m, m1t_l);
  k_wsplit3<<<128, 256, 0, stream>>>(mw2, 128, 256, m2t_h, m2t_m, m2t_l);
  k_node_enc<<<16384, 256, 0, stream>>>(nf, new_w, new_b, h0);

  for (int t = 0; t < 3; ++t) {
    const float* hprev = h0;
    for (int p = 1; p <= 5; ++p) {
      if (t > 0 && p > 1)
        k_mlp2m<256, false, false, true, false><<<1024, 256, 0, stream>>>(
            hprev, nullptr, nullptr, nullptr,
            parts + (long)(p - 1) * ND, nullptr, nullptr, nullptr,
            cw1t_h, cw1t_m, cw1t_l, cb1, nullptr, nullptr,
            cw2t_h, cw2t_m, cw2t_l, cb2, nullptr, chp, cmp, clp);
      else
        k_mlp2m<128, false, false, true, false><<<1024, 256, 0, stream>>>(
            hprev, nullptr, nullptr, nullptr, nullptr, nullptr, nullptr, nullptr,
            cw1t_h, cw1t_m, cw1t_l, cb1, nullptr, nullptr,
            cw2t_h, cw2t_m, cw2t_l, cb2, nullptr, chp, cmp, clp);
      k_edgeb<<<dim3(512, 4), 256, 0, stream>>>(chp, cmp, clp, efp,
                                                m1t_h, m1t_m, m1t_l,
                                                Wfold, bfold, csr_f, rp_g, ag);
      float* hnew = parts + (long)(p - 1) * ND;
      k_mlp2m<256, true, true, false, true><<<1024, 256, 0, stream>>>(
          nullptr, chp, cmp, clp, ag, m2t_h, m2t_m, m2t_l,
          nw1t_h, nw1t_m, nw1t_l, nb1, deg, vbias,
          nw2t_h, nw2t_m, nw2t_l, nb2, hnew, nullptr, nullptr, nullptr);
      hprev = hnew;
    }
    k_tfeat<<<8192, 256, 0, stream>>>(parts + 4 * ND, t1w, t1b, t2w, t2b, tf);
    k_sim<<<256, 256, 0, stream>>>(tf, sim);
    k_sink<<<256, 256, 0, stream>>>(sim, outp);
    if (t < 2) {
      for (int pi = 3; pi >= 0; --pi)
        k_mix<<<256, 256, 0, stream>>>(sim, parts + (long)pi * ND, parts + (long)(pi + 1) * ND);
    }
  }
}

// Round 18
// 5838.195 us; speedup vs baseline: 1.0005x; 1.0005x over previous
//
#include <hip/hip_runtime.h>
#include <hip/hip_bf16.h>

#define NNODES   32768
#define NGROUPS  512
#define EPG      512
#define ND       (32768l*128)

typedef __attribute__((ext_vector_type(4))) float f32x4;
typedef __attribute__((ext_vector_type(8))) short bf16x8;

__device__ __forceinline__ short f2bf(float x) {
  unsigned u = __float_as_uint(x);
  unsigned r = (u + 0x7FFF + ((u >> 16) & 1)) >> 16;   // RNE
  return (short)r;
}
__device__ __forceinline__ float bf2f(short h) {
  return __uint_as_float(((unsigned)(unsigned short)h) << 16);
}
// 3-term bf16 split: x ~= h + m + l  (covers ~24 mantissa bits)
__device__ __forceinline__ void split3(float x, short* ph, short* pm, short* pl, long idx) {
  short h = f2bf(x); float r1 = x - bf2f(h);
  short m = f2bf(r1); float r2 = r1 - bf2f(m);
  ph[idx] = h; pm[idx] = m; pl[idx] = f2bf(r2);
}

// ---------------------------------------------------------------------------
// h0 = node_features(32768x32) @ W(32x128) + b
__global__ void k_node_enc(const float* __restrict__ nf, const float* __restrict__ w,
                           const float* __restrict__ b, float* __restrict__ h0) {
  int idx = blockIdx.x * 256 + threadIdx.x;
  int row = idx >> 7, col = idx & 127;
  const float* x = nf + row * 32;
  float acc = b[col];
#pragma unroll
  for (int k = 0; k < 32; ++k) acc = fmaf(x[k], w[k * 128 + col], acc);
  h0[idx] = acc;
}

// ---------------------------------------------------------------------------
// Folded weights (fp32):
//  blocks 0..15 : Wfold[16][256] = eew(16x64) @ mw1[256:320,:]
//  block  16    : bfold[256]     = eeb @ mw1[256:320,:] + mb1
//  block  17    : vbias[256]     = mb2 @ nw1[128:256,:]
__global__ void k_prep(const float* __restrict__ eew, const float* __restrict__ eeb,
                       const float* __restrict__ mw1, const float* __restrict__ mb1,
                       const float* __restrict__ mb2, const float* __restrict__ nw1,
                       float* __restrict__ Wfold, float* __restrict__ bfold,
                       float* __restrict__ vbias) {
  const int c = threadIdx.x, b = blockIdx.x;
  if (b < 16) {
    float a = 0.f;
    for (int j = 0; j < 64; ++j) a = fmaf(eew[b * 64 + j], mw1[(256 + j) * 256 + c], a);
    Wfold[b * 256 + c] = a;
  } else if (b == 16) {
    float a = mb1[c];
    for (int j = 0; j < 64; ++j) a = fmaf(eeb[j], mw1[(256 + j) * 256 + c], a);
    bfold[c] = a;
  } else {
    float a = 0.f;
    for (int j = 0; j < 128; ++j) a = fmaf(mb2[j], nw1[(128 + j) * 256 + c], a);
    vbias[c] = a;
  }
}

// ---------------------------------------------------------------------------
// Weight transpose + bf16x3 split: W (>=Kd x C row-major) -> Wt[c][k], k-stride 256
__global__ void k_wsplit3(const float* __restrict__ W, int C, int Kd,
                          short* __restrict__ th, short* __restrict__ tm,
                          short* __restrict__ tl) {
  const int c = blockIdx.x;
  for (int k = threadIdx.x; k < Kd; k += 256) {
    float w = W[(long)k * C + c];
    split3(w, th, tm, tl, c * 256 + k);
  }
}

// ---------------------------------------------------------------------------
// Deterministic CSR per group: edges stably sorted by to-node.
__global__ void k_csr(const int* __restrict__ from_idx, const int* __restrict__ to_idx,
                      const float* __restrict__ ef,
                      int* __restrict__ csr_f, int* __restrict__ rp_g,
                      float* __restrict__ efp, int* __restrict__ deg) {
  __shared__ int cnt[64], rps[65];
  __shared__ int tls[EPG], fls[EPG];
  __shared__ short ord[EPG];
  const int g = blockIdx.x, tid = threadIdx.x;
  const int be = g * EPG, bn = g * 64;
  if (tid < 64) cnt[tid] = 0;
  __syncthreads();
  for (int e = tid; e < EPG; e += 256) {
    int t = to_idx[be + e] - bn;
    tls[e] = t;
    fls[e] = from_idx[be + e] - bn;
    atomicAdd(&cnt[t], 1);
  }
  __syncthreads();
  if (tid == 0) {
    int s = 0;
    for (int i = 0; i < 64; ++i) { rps[i] = s; s += cnt[i]; }
    rps[64] = s;
  }
  __syncthreads();
  if (tid < 64) {
    int pos = rps[tid];
    for (int e = 0; e < EPG; ++e)
      if (tls[e] == tid) ord[pos++] = (short)e;
  }
  __syncthreads();
  for (int ec = tid; ec < EPG; ec += 256) {
    const int eo = ord[ec];
    csr_f[be + ec] = fls[eo];
    const float4* src = (const float4*)&ef[(long)(be + eo) * 16];
    float4* dst = (float4*)&efp[(long)(be + ec) * 16];
    dst[0] = src[0]; dst[1] = src[1]; dst[2] = src[2]; dst[3] = src[3];
  }
  if (tid < 65) rp_g[g * 65 + tid] = rps[tid];
  if (tid < 64) deg[bn + tid] = cnt[tid];
}

// ---------------------------------------------------------------------------
// MFMA bf16x3 2-layer MLP. X = [x0 | x1].
// RPX0: x0 read from pre-split planes. WPOUT: output written as bf16x3 planes.
// AGG: x1 is ag (N x 256); a pre-phase computes agg = ag @ mw2 via MFMA
//      (two-chain, bit-identical to the former k_aggm) and stages it as
//      bf16x3 into cols 128..255 of the staging buffer.
template<int KTOT, bool DEG, bool RPX0, bool WPOUT, bool AGG>
__global__ __launch_bounds__(256, 3)
void k_mlp2m(const float* __restrict__ x0,
             const short* __restrict__ x0h, const short* __restrict__ x0m,
             const short* __restrict__ x0l,
             const float* __restrict__ x1,
             const short* __restrict__ A2h, const short* __restrict__ A2m,
             const short* __restrict__ A2l,
             const short* __restrict__ W1h, const short* __restrict__ W1m,
             const short* __restrict__ W1l,
             const float* __restrict__ b1, const int* __restrict__ deg,
             const float* __restrict__ vbias,
             const short* __restrict__ W2h, const short* __restrict__ W2m,
             const short* __restrict__ W2l,
             const float* __restrict__ b2,
             float* __restrict__ out,
             short* __restrict__ outh, short* __restrict__ outm,
             short* __restrict__ outl) {
  __shared__ short xh[32 * 264];
  __shared__ short xm[32 * 264];
  __shared__ short xl[32 * 264];
  __shared__ int degs[32];
  const int tid = threadIdx.x;
  const long row0 = (long)blockIdx.x * 32;

  const int lane = tid & 63, wid = tid >> 6;
  const int lr = lane & 15;
  const int lk = (lane >> 4) * 8;
  const int rsub = (lane >> 4) * 4;

  if constexpr (AGG) {
    // pre-phase: agg(32x128) = ag(32x256) @ mw2, two accumulation chains
    for (int i = tid; i < 2048; i += 256) {
      const int r = i >> 6, q = i & 63;
      float4 v = *(const float4*)&x1[(row0 + r) * 256 + q * 4];
      const int base = r * 264 + q * 4;
      split3(v.x, xh, xm, xl, base + 0);
      split3(v.y, xh, xm, xl, base + 1);
      split3(v.z, xh, xm, xl, base + 2);
      split3(v.w, xh, xm, xl, base + 3);
    }
    __syncthreads();

    f32x4 s0[2][2], s1[2][2];
#pragma unroll
    for (int fc = 0; fc < 2; ++fc)
#pragma unroll
      for (int fr = 0; fr < 2; ++fr) { s0[fr][fc] = {0.f,0.f,0.f,0.f}; s1[fr][fc] = {0.f,0.f,0.f,0.f}; }

#pragma unroll 2
    for (int ks = 0; ks < 4; ++ks) {          // K half 0: 0..127
      const int k0 = ks * 32 + lk;
      bf16x8 ah[2], am[2], al[2];
#pragma unroll
      for (int fr = 0; fr < 2; ++fr) {
        const int ab = (fr * 16 + lr) * 264 + k0;
        ah[fr] = *(const bf16x8*)&xh[ab];
        am[fr] = *(const bf16x8*)&xm[ab];
        al[fr] = *(const bf16x8*)&xl[ab];
      }
#pragma unroll
      for (int fc = 0; fc < 2; ++fc) {
        const long wrow = (long)(wid * 32 + fc * 16 + lr) * 256 + k0;
        const bf16x8 bh = *(const bf16x8*)&A2h[wrow];
        const bf16x8 bm = *(const bf16x8*)&A2m[wrow];
        const bf16x8 bl = *(const bf16x8*)&A2l[wrow];
#pragma unroll
        for (int fr = 0; fr < 2; ++fr) {
          s0[fr][fc] = __builtin_amdgcn_mfma_f32_16x16x32_bf16(ah[fr], bh, s0[fr][fc], 0, 0, 0);
          s0[fr][fc] = __builtin_amdgcn_mfma_f32_16x16x32_bf16(ah[fr], bm, s0[fr][fc], 0, 0, 0);
          s0[fr][fc] = __builtin_amdgcn_mfma_f32_16x16x32_bf16(am[fr], bh, s0[fr][fc], 0, 0, 0);
          s0[fr][fc] = __builtin_amdgcn_mfma_f32_16x16x32_bf16(ah[fr], bl, s0[fr][fc], 0, 0, 0);
          s0[fr][fc] = __builtin_amdgcn_mfma_f32_16x16x32_bf16(am[fr], bm, s0[fr][fc], 0, 0, 0);
          s0[fr][fc] = __builtin_amdgcn_mfma_f32_16x16x32_bf16(al[fr], bh, s0[fr][fc], 0, 0, 0);
        }
      }
    }
#pragma unroll 2
    for (int ks = 4; ks < 8; ++ks) {          // K half 1: 128..255
      const int k0 = ks * 32 + lk;
      bf16x8 ah[2], am[2], al[2];
#pragma unroll
      for (int fr = 0; fr < 2; ++fr) {
        const int ab = (fr * 16 + lr) * 264 + k0;
        ah[fr] = *(const bf16x8*)&xh[ab];
        am[fr] = *(const bf16x8*)&xm[ab];
        al[fr] = *(const bf16x8*)&xl[ab];
      }
#pragma unroll
      for (int fc = 0; fc < 2; ++fc) {
        const long wrow = (long)(wid * 32 + fc * 16 + lr) * 256 + k0;
        const bf16x8 bh = *(const bf16x8*)&A2h[wrow];
        const bf16x8 bm = *(const bf16x8*)&A2m[wrow];
        const bf16x8 bl = *(const bf16x8*)&A2l[wrow];
#pragma unroll
        for (int fr = 0; fr < 2; ++fr) {
          s1[fr][fc] = __builtin_amdgcn_mfma_f32_16x16x32_bf16(ah[fr], bh, s1[fr][fc], 0, 0, 0);
          s1[fr][fc] = __builtin_amdgcn_mfma_f32_16x16x32_bf16(ah[fr], bm, s1[fr][fc], 0, 0, 0);
          s1[fr][fc] = __builtin_amdgcn_mfma_f32_16x16x32_bf16(am[fr], bh, s1[fr][fc], 0, 0, 0);
          s1[fr][fc] = __builtin_amdgcn_mfma_f32_16x16x32_bf16(ah[fr], bl, s1[fr][fc], 0, 0, 0);
          s1[fr][fc] = __builtin_amdgcn_mfma_f32_16x16x32_bf16(am[fr], bm, s1[fr][fc], 0, 0, 0);
          s1[fr][fc] = __builtin_amdgcn_mfma_f32_16x16x32_bf16(al[fr], bh, s1[fr][fc], 0, 0, 0);
        }
      }
    }
    __syncthreads();   // all ag reads done before staging overwrite

    // split3(agg) into cols 128..255 (same value as old global round-trip)
#pragma unroll
    for (int fr = 0; fr < 2; ++fr)
#pragma unroll
      for (int fc = 0; fc < 2; ++fc) {
        const int col = wid * 32 + fc * 16 + lr;
#pragma unroll
        for (int r = 0; r < 4; ++r) {
          const int row = fr * 16 + rsub + r;
          split3(s0[fr][fc][r] + s1[fr][fc][r], xh, xm, xl, row * 264 + 128 + col);
        }
      }
  }

  if constexpr (RPX0) {
    for (int i = tid; i < 32 * 16; i += 256) {
      const int r = i >> 4, q = i & 15;
      const long gb = (row0 + r) * 128 + q * 8;
      const int lb = r * 264 + q * 8;
      *(bf16x8*)&xh[lb] = *(const bf16x8*)&x0h[gb];
      *(bf16x8*)&xm[lb] = *(const bf16x8*)&x0m[gb];
      *(bf16x8*)&xl[lb] = *(const bf16x8*)&x0l[gb];
    }
  } else {
    for (int i = tid; i < 32 * 32; i += 256) {
      const int r = i >> 5, q = i & 31;
      float4 v = *(const float4*)&x0[(row0 + r) * 128 + q * 4];
      const int base = r * 264 + q * 4;
      split3(v.x, xh, xm, xl, base + 0);
      split3(v.y, xh, xm, xl, base + 1);
      split3(v.z, xh, xm, xl, base + 2);
      split3(v.w, xh, xm, xl, base + 3);
    }
  }
  if constexpr (KTOT == 256 && !AGG) {
    for (int i = tid; i < 32 * 32; i += 256) {
      const int r = i >> 5, q = i & 31;
      float4 v = *(const float4*)&x1[(row0 + r) * 128 + q * 4];
      const int base = r * 264 + 128 + q * 4;
      split3(v.x, xh, xm, xl, base + 0);
      split3(v.y, xh, xm, xl, base + 1);
      split3(v.z, xh, xm, xl, base + 2);
      split3(v.w, xh, xm, xl, base + 3);
    }
  }
  if constexpr (DEG) { if (tid < 32) degs[tid] = deg[row0 + tid]; }
  __syncthreads();

  // ---- layer 1: 32 x 256, wave cols [wid*64, wid*64+64) ----
  f32x4 acc[2][4];
#pragma unroll
  for (int fc = 0; fc < 4; ++fc) {
    const int col = wid * 64 + fc * 16 + lr;
    const float bv = b1[col];
#pragma unroll
    for (int fr = 0; fr < 2; ++fr) acc[fr][fc] = {bv, bv, bv, bv};
    if constexpr (DEG) {
      const float vb = vbias[col];
#pragma unroll
      for (int fr = 0; fr < 2; ++fr)
#pragma unroll
        for (int r = 0; r < 4; ++r)
          acc[fr][fc][r] += (float)degs[fr * 16 + rsub + r] * vb;
    }
  }

#pragma unroll 2
  for (int ks = 0; ks < KTOT / 32; ++ks) {
    const int k0 = ks * 32 + lk;
    bf16x8 ah[2], am[2], al[2];
#pragma unroll
    for (int fr = 0; fr < 2; ++fr) {
      const int ab = (fr * 16 + lr) * 264 + k0;
      ah[fr] = *(const bf16x8*)&xh[ab];
      am[fr] = *(const bf16x8*)&xm[ab];
      al[fr] = *(const bf16x8*)&xl[ab];
    }
#pragma unroll
    for (int fc = 0; fc < 4; ++fc) {
      const long wrow = (long)(wid * 64 + fc * 16 + lr) * 256 + k0;
      const bf16x8 bh = *(const bf16x8*)&W1h[wrow];
      const bf16x8 bm = *(const bf16x8*)&W1m[wrow];
      const bf16x8 bl = *(const bf16x8*)&W1l[wrow];
#pragma unroll
      for (int fr = 0; fr < 2; ++fr) {
        acc[fr][fc] = __builtin_amdgcn_mfma_f32_16x16x32_bf16(ah[fr], bh, acc[fr][fc], 0, 0, 0);
        acc[fr][fc] = __builtin_amdgcn_mfma_f32_16x16x32_bf16(ah[fr], bm, acc[fr][fc], 0, 0, 0);
        acc[fr][fc] = __builtin_amdgcn_mfma_f32_16x16x32_bf16(am[fr], bh, acc[fr][fc], 0, 0, 0);
        acc[fr][fc] = __builtin_amdgcn_mfma_f32_16x16x32_bf16(ah[fr], bl, acc[fr][fc], 0, 0, 0);
        acc[fr][fc] = __builtin_amdgcn_mfma_f32_16x16x32_bf16(am[fr], bm, acc[fr][fc], 0, 0, 0);
        acc[fr][fc] = __builtin_amdgcn_mfma_f32_16x16x32_bf16(al[fr], bh, acc[fr][fc], 0, 0, 0);
      }
    }
  }
  __syncthreads();

  // relu + split3 + store hidden to LDS [row][hcol]
#pragma unroll
  for (int fr = 0; fr < 2; ++fr)
#pragma unroll
    for (int fc = 0; fc < 4; ++fc) {
      const int col = wid * 64 + fc * 16 + lr;
#pragma unroll
      for (int r = 0; r < 4; ++r) {
        const int row = fr * 16 + rsub + r;
        float v = fmaxf(acc[fr][fc][r], 0.f);
        split3(v, xh, xm, xl, row * 264 + col);
      }
    }
  __syncthreads();

  // ---- layer 2: 32 x 128, wave cols [wid*32, wid*32+32) ----
  f32x4 acc2[2][2];
#pragma unroll
  for (int fc = 0; fc < 2; ++fc) {
    const float bv = b2[wid * 32 + fc * 16 + lr];
#pragma unroll
    for (int fr = 0; fr < 2; ++fr) acc2[fr][fc] = {bv, bv, bv, bv};
  }
#pragma unroll 2
  for (int ks = 0; ks < 8; ++ks) {
    const int k0 = ks * 32 + lk;
    bf16x8 ah[2], am[2], al[2];
#pragma unroll
    for (int fr = 0; fr < 2; ++fr) {
      const int ab = (fr * 16 + lr) * 264 + k0;
      ah[fr] = *(const bf16x8*)&xh[ab];
      am[fr] = *(const bf16x8*)&xm[ab];
      al[fr] = *(const bf16x8*)&xl[ab];
    }
#pragma unroll
    for (int fc = 0; fc < 2; ++fc) {
      const long wrow = (long)(wid * 32 + fc * 16 + lr) * 256 + k0;
      const bf16x8 bh = *(const bf16x8*)&W2h[wrow];
      const bf16x8 bm = *(const bf16x8*)&W2m[wrow];
      const bf16x8 bl = *(const bf16x8*)&W2l[wrow];
#pragma unroll
      for (int fr = 0; fr < 2; ++fr) {
        acc2[fr][fc] = __builtin_amdgcn_mfma_f32_16x16x32_bf16(ah[fr], bh, acc2[fr][fc], 0, 0, 0);
        acc2[fr][fc] = __builtin_amdgcn_mfma_f32_16x16x32_bf16(ah[fr], bm, acc2[fr][fc], 0, 0, 0);
        acc2[fr][fc] = __builtin_amdgcn_mfma_f32_16x16x32_bf16(am[fr], bh, acc2[fr][fc], 0, 0, 0);
        acc2[fr][fc] = __builtin_amdgcn_mfma_f32_16x16x32_bf16(ah[fr], bl, acc2[fr][fc], 0, 0, 0);
        acc2[fr][fc] = __builtin_amdgcn_mfma_f32_16x16x32_bf16(am[fr], bm, acc2[fr][fc], 0, 0, 0);
        acc2[fr][fc] = __builtin_amdgcn_mfma_f32_16x16x32_bf16(al[fr], bh, acc2[fr][fc], 0, 0, 0);
      }
    }
  }
#pragma unroll
  for (int fr = 0; fr < 2; ++fr)
#pragma unroll
    for (int fc = 0; fc < 2; ++fc) {
      const int col = wid * 32 + fc * 16 + lr;
#pragma unroll
      for (int r = 0; r < 4; ++r) {
        const long gi = (row0 + fr * 16 + rsub + r) * 128 + col;
        if constexpr (WPOUT) {
          split3(acc2[fr][fc][r], outh, outm, outl, gi);
        } else {
          out[gi] = acc2[fr][fc][r];
        }
      }
    }
}

// ---------------------------------------------------------------------------
// Edge kernel, phases a+b. grid (512, 4): block = (group, 64-col block).
// phase a: cA/cB = comb_planes @ mw1t[cb] (MFMA) -> LDS.
// phase b: CSR edge loop (3-edge ILP) -> hidden-sum written to global ag (N x 256).
// waves_per_eu(4,4): 128-reg budget >= measured 84-reg demand; LDS 36.3KB*4 <= 160KB
// -> 4 blocks/CU without the (256,4) 64-reg spill pathology seen in round 17.
__global__ __attribute__((amdgpu_waves_per_eu(4, 4))) __launch_bounds__(256)
void k_edgeb(const short* __restrict__ chp, const short* __restrict__ cmp,
             const short* __restrict__ clp,
             const float* __restrict__ efp,
             const short* __restrict__ m1h, const short* __restrict__ m1m,
             const short* __restrict__ m1l,
             const float* __restrict__ Wfold, const float* __restrict__ bfold,
             const int* __restrict__ csr_f, const int* __restrict__ rp_g,
             float* __restrict__ ag) {
  __shared__ __align__(16) float cAB[2 * 64 * 68];   // cA | cB
  __shared__ short fl[EPG];
  __shared__ int rp[65];
  float* cA = cAB;
  float* cB = cAB + 64 * 68;

  const int tid = threadIdx.x;
  const int g = blockIdx.x, cb = blockIdx.y;
  const int be = g * EPG, bn = g * 64;
  const int col0 = cb * 64;

  for (int i = tid; i < EPG; i += 256) fl[i] = (short)csr_f[be + i];
  if (tid < 65) rp[tid] = rp_g[g * 65 + tid];

  const int lane = tid & 63, wid = tid >> 6;
  const int lr = lane & 15;
  const int lk = (lane >> 4) * 8;
  const int rsub = (lane >> 4) * 4;
  const int ng = tid >> 4, cg = tid & 15;
  const int n0 = ng * 4, cq = cg * 4;

  // phase a: waves 0,1 -> cA (mw1 k 0..127); waves 2,3 -> cB (k 128..255).
  {
    const int isB = wid >> 1;
    const int cw = (wid & 1) * 32;
    const int wkof = isB * 128;
    float* dstC = isB ? cB : cA;
#pragma unroll 1
    for (int hf = 0; hf < 2; ++hf) {
      f32x4 c[2][2];
#pragma unroll
      for (int fr = 0; fr < 2; ++fr)
#pragma unroll
        for (int fc = 0; fc < 2; ++fc) c[fr][fc] = {0.f, 0.f, 0.f, 0.f};
      for (int ks = 0; ks < 4; ++ks) {
        const int k0 = ks * 32 + lk;
        bf16x8 ah[2], am[2], al[2];
#pragma unroll
        for (int fr = 0; fr < 2; ++fr) {
          const long ga = (long)(bn + (hf * 2 + fr) * 16 + lr) * 128 + k0;
          ah[fr] = *(const bf16x8*)&chp[ga];
          am[fr] = *(const bf16x8*)&cmp[ga];
          al[fr] = *(const bf16x8*)&clp[ga];
        }
#pragma unroll
        for (int fc = 0; fc < 2; ++fc) {
          const long wrow = (long)(col0 + cw + fc * 16 + lr) * 256 + wkof + k0;
          const bf16x8 bh = *(const bf16x8*)&m1h[wrow];
          const bf16x8 bm = *(const bf16x8*)&m1m[wrow];
          const bf16x8 bl = *(const bf16x8*)&m1l[wrow];
#pragma unroll
          for (int fr = 0; fr < 2; ++fr) {
            c[fr][fc] = __builtin_amdgcn_mfma_f32_16x16x32_bf16(ah[fr], bh, c[fr][fc], 0, 0, 0);
            c[fr][fc] = __builtin_amdgcn_mfma_f32_16x16x32_bf16(ah[fr], bm, c[fr][fc], 0, 0, 0);
            c[fr][fc] = __builtin_amdgcn_mfma_f32_16x16x32_bf16(am[fr], bh, c[fr][fc], 0, 0, 0);
            c[fr][fc] = __builtin_amdgcn_mfma_f32_16x16x32_bf16(ah[fr], bl, c[fr][fc], 0, 0, 0);
            c[fr][fc] = __builtin_amdgcn_mfma_f32_16x16x32_bf16(am[fr], bm, c[fr][fc], 0, 0, 0);
            c[fr][fc] = __builtin_amdgcn_mfma_f32_16x16x32_bf16(al[fr], bh, c[fr][fc], 0, 0, 0);
          }
        }
      }
#pragma unroll
      for (int fr = 0; fr < 2; ++fr)
#pragma unroll
        for (int fc = 0; fc < 2; ++fc) {
          const int col = cw + fc * 16 + lr;
#pragma unroll
          for (int r = 0; r < 4; ++r)
            dstC[((hf * 2 + fr) * 16 + rsub + r) * 68 + col] = c[fr][fc][r];
        }
    }
  }
  float4 Wf[16];
#pragma unroll
  for (int k = 0; k < 16; ++k) Wf[k] = *(const float4*)&Wfold[k * 256 + col0 + cq];
  const float4 bf = *(const float4*)&bfold[col0 + cq];
  __syncthreads();   // cA/cB + fl/rp visible

  // phase b: edge phase (fp32 CSR, atomic-free, 3-edge ILP) -> global ag
#pragma unroll
  for (int i = 0; i < 4; ++i) {
    const int n = n0 + i;
    const float4 cBn = *(const float4*)&cB[n * 68 + cq];
    const int eEnd = rp[n + 1];
    float4 a0 = make_float4(0.f, 0.f, 0.f, 0.f);
    float4 a1 = make_float4(0.f, 0.f, 0.f, 0.f);
    float4 a2 = make_float4(0.f, 0.f, 0.f, 0.f);
    int e = rp[n];
    for (; e + 2 < eEnd; e += 3) {
      const int f0 = fl[e], f1 = fl[e + 1], f2 = fl[e + 2];
      const float* er0 = efp + (long)(be + e) * 16;
      const float* er1 = efp + (long)(be + e + 1) * 16;
      const float* er2 = efp + (long)(be + e + 2) * 16;
      float4 ea[4], eb[4], ec[4];
#pragma unroll
      for (int kq = 0; kq < 4; ++kq) {
        ea[kq] = ((const float4*)er0)[kq];
        eb[kq] = ((const float4*)er1)[kq];
        ec[kq] = ((const float4*)er2)[kq];
      }
      float4 h0 = bf, h1 = bf, h2 = bf;
#pragma unroll
      for (int kq = 0; kq < 4; ++kq) {
        const float ev0[4] = {ea[kq].x, ea[kq].y, ea[kq].z, ea[kq].w};
        const float ev1[4] = {eb[kq].x, eb[kq].y, eb[kq].z, eb[kq].w};
        const float ev2[4] = {ec[kq].x, ec[kq].y, ec[kq].z, ec[kq].w};
#pragma unroll
        for (int s = 0; s < 4; ++s) {
          const float4 w = Wf[kq * 4 + s];
          h0.x = fmaf(ev0[s], w.x, h0.x); h0.y = fmaf(ev0[s], w.y, h0.y);
          h0.z = fmaf(ev0[s], w.z, h0.z); h0.w = fmaf(ev0[s], w.w, h0.w);
          h1.x = fmaf(ev1[s], w.x, h1.x); h1.y = fmaf(ev1[s], w.y, h1.y);
          h1.z = fmaf(ev1[s], w.z, h1.z); h1.w = fmaf(ev1[s], w.w, h1.w);
          h2.x = fmaf(ev2[s], w.x, h2.x); h2.y = fmaf(ev2[s], w.y, h2.y);
          h2.z = fmaf(ev2[s], w.z, h2.z); h2.w = fmaf(ev2[s], w.w, h2.w);
        }
      }
      const float4 va0 = *(const float4*)&cA[f0 * 68 + cq];
      const float4 va1 = *(const float4*)&cA[f1 * 68 + cq];
      const float4 va2 = *(const float4*)&cA[f2 * 68 + cq];
      a0.x += fmaxf(h0.x + va0.x + cBn.x, 0.f);
      a0.y += fmaxf(h0.y + va0.y + cBn.y, 0.f);
      a0.z += fmaxf(h0.z + va0.z + cBn.z, 0.f);
      a0.w += fmaxf(h0.w + va0.w + cBn.w, 0.f);
      a1.x += fmaxf(h1.x + va1.x + cBn.x, 0.f);
      a1.y += fmaxf(h1.y + va1.y + cBn.y, 0.f);
      a1.z += fmaxf(h1.z + va1.z + cBn.z, 0.f);
      a1.w += fmaxf(h1.w + va1.w + cBn.w, 0.f);
      a2.x += fmaxf(h2.x + va2.x + cBn.x, 0.f);
      a2.y += fmaxf(h2.y + va2.y + cBn.y, 0.f);
      a2.z += fmaxf(h2.z + va2.z + cBn.z, 0.f);
      a2.w += fmaxf(h2.w + va2.w + cBn.w, 0.f);
    }
    for (; e < eEnd; ++e) {   // tail (0..2 edges)
      const int f = fl[e];
      const float* er = efp + (long)(be + e) * 16;
      float4 h = bf;
#pragma unroll
      for (int kq = 0; kq < 4; ++kq) {
        const float4 e4 = ((const float4*)er)[kq];
        const float ev[4] = {e4.x, e4.y, e4.z, e4.w};
#pragma unroll
        for (int s = 0; s < 4; ++s) {
          const float4 w = Wf[kq * 4 + s];
          h.x = fmaf(ev[s], w.x, h.x); h.y = fmaf(ev[s], w.y, h.y);
          h.z = fmaf(ev[s], w.z, h.z); h.w = fmaf(ev[s], w.w, h.w);
        }
      }
      const float4 va = *(const float4*)&cA[f * 68 + cq];
      a0.x += fmaxf(h.x + va.x + cBn.x, 0.f);
      a0.y += fmaxf(h.y + va.y + cBn.y, 0.f);
      a0.z += fmaxf(h.z + va.z + cBn.z, 0.f);
      a0.w += fmaxf(h.w + va.w + cBn.w, 0.f);
    }
    a0.x += a1.x; a0.y += a1.y; a0.z += a1.z; a0.w += a1.w;
    a0.x += a2.x; a0.y += a2.y; a0.z += a2.z; a0.w += a2.w;
    *(float4*)&ag[(long)(bn + n) * 256 + col0 + cq] = a0;
  }
}

// ---------------------------------------------------------------------------
__global__ void k_tfeat(const float* __restrict__ x,
                        const float* __restrict__ t1w, const float* __restrict__ t1b,
                        const float* __restrict__ t2w, const float* __restrict__ t2b,
                        float* __restrict__ tf) {
  __shared__ float xs[4][128];
  __shared__ float ys[4][64];
  const int tid = threadIdx.x;
  const long row0 = (long)blockIdx.x * 4;
  for (int i = tid; i < 512; i += 256)
    xs[i >> 7][i & 127] = x[(row0 + (i >> 7)) * 128 + (i & 127)];
  __syncthreads();
  const int r = tid >> 6, c = tid & 63;
  float acc = t1b[c];
#pragma unroll 4
  for (int k = 0; k < 128; ++k) acc = fmaf(xs[r][k], t1w[k * 64 + c], acc);
  ys[r][c] = fmaxf(acc, 0.f);
  __syncthreads();
  float a2 = t2b[c];
#pragma unroll 4
  for (int k = 0; k < 64; ++k) a2 = fmaf(ys[r][k], t2w[k * 64 + c], a2);
  tf[(row0 + r) * 64 + c] = a2;
}

// ---------------------------------------------------------------------------
__global__ void k_sim(const float* __restrict__ tf, float* __restrict__ sim) {
  const int b = blockIdx.x, tid = threadIdx.x;
  __shared__ float tq[64][65];
  __shared__ float tcs[64][65];
  for (int i = tid; i < 4096; i += 256) {
    tq[i >> 6][i & 63]  = tf[(long)b * 8192 + i];
    tcs[i >> 6][i & 63] = tf[(long)b * 8192 + 4096 + i];
  }
  __syncthreads();
  const int m = tid >> 2, j0 = (tid & 3) * 16;
#pragma unroll
  for (int j = 0; j < 16; ++j) {
    float a = 0.f;
#pragma unroll 4
    for (int k = 0; k < 64; ++k) a = fmaf(tq[m][k], tcs[j0 + j][k], a);
    sim[(long)b * 4096 + m * 64 + j0 + j] = a;
  }
}

// ---------------------------------------------------------------------------
__global__ void k_sink(float* __restrict__ sim, float* __restrict__ outp) {
  const int b = blockIdx.x, tid = threadIdx.x;
  __shared__ float la[64][65];
  const float C = 14.426950408889634f;   // 10 / ln(2)
  for (int i = tid; i < 4096; i += 256)
    la[i >> 6][i & 63] = sim[(long)b * 4096 + i] * C;
  __syncthreads();
  const int r4 = tid >> 2, l4 = tid & 3;
  for (int it = 0; it < 20; ++it) {
    {
      float m = -3.4e38f;
#pragma unroll
      for (int i = 0; i < 16; ++i) m = fmaxf(m, la[r4][l4 + 4 * i]);
      m = fmaxf(m, __shfl_xor(m, 1)); m = fmaxf(m, __shfl_xor(m, 2));
      float s = 0.f;
#pragma unroll
      for (int i = 0; i < 16; ++i) s += exp2f(la[r4][l4 + 4 * i] - m);
      s += __shfl_xor(s, 1); s += __shfl_xor(s, 2);
      const float lse = m + log2f(s);
#pragma unroll
      for (int i = 0; i < 16; ++i) la[r4][l4 + 4 * i] -= lse;
    }
    __syncthreads();
    {
      float m = -3.4e38f;
#pragma unroll
      for (int i = 0; i < 16; ++i) m = fmaxf(m, la[l4 + 4 * i][r4]);
      m = fmaxf(m, __shfl_xor(m, 1)); m = fmaxf(m, __shfl_xor(m, 2));
      float s = 0.f;
#pragma unroll
      for (int i = 0; i < 16; ++i) s += exp2f(la[l4 + 4 * i][r4] - m);
      s += __shfl_xor(s, 1); s += __shfl_xor(s, 2);
      const float lse = m + log2f(s);
#pragma unroll
      for (int i = 0; i < 16; ++i) la[l4 + 4 * i][r4] -= lse;
    }
    __syncthreads();
  }
  for (int i = tid; i < 4096; i += 256) {
    const float v = exp2f(la[i >> 6][i & 63]);
    outp[(long)b * 4096 + i] = v;
    sim[(long)b * 4096 + i] = v;
  }
}

// ---------------------------------------------------------------------------
__global__ void k_mix(const float* __restrict__ plan, const float* __restrict__ src,
                      float* __restrict__ dst) {
  const int b = blockIdx.x, tid = threadIdx.x;
  __shared__ float pl[64][65];
  __shared__ float qs[64][128];
  __shared__ float cs[64][128];
  const long qbase = (long)(2 * b) * 64, cbase = qbase + 64;
  for (int i = tid; i < 4096; i += 256) pl[i >> 6][i & 63] = plan[(long)b * 4096 + i];
  for (int i = tid; i < 8192; i += 256) {
    qs[i >> 7][i & 127] = src[qbase * 128 + i];
    cs[i >> 7][i & 127] = src[cbase * 128 + i];
  }
  __syncthreads();
  const int d = tid & 127, m0 = (tid >> 7) * 32;
  for (int m = m0; m < m0 + 32; ++m) {
    float a = 0.f;
#pragma unroll 4
    for (int j = 0; j < 64; ++j) a = fmaf(pl[m][j], cs[j][d], a);
    dst[(qbase + m) * 128 + d] = a;
  }
  for (int j = m0; j < m0 + 32; ++j) {
    float a = 0.f;
#pragma unroll 4
    for (int m = 0; m < 64; ++m) a = fmaf(pl[m][j], qs[m][d], a);
    dst[(cbase + j) * 128 + d] = a;
  }
}

// ---------------------------------------------------------------------------
extern "C" void kernel_launch(void* const* d_in, const int* in_sizes, int n_in,
                              void* d_out, int out_size, void* d_ws, size_t ws_size,
                              hipStream_t stream) {
  const float* nf  = (const float*)d_in[0];
  const float* ef  = (const float*)d_in[1];
  const int* from_idx = (const int*)d_in[2];
  const int* to_idx   = (const int*)d_in[3];
  const float* new_w = (const float*)d_in[4];
  const float* new_b = (const float*)d_in[5];
  const float* eew = (const float*)d_in[6];
  const float* eeb = (const float*)d_in[7];
  const float* mw1 = (const float*)d_in[8];
  const float* mb1 = (const float*)d_in[9];
  const float* mw2 = (const float*)d_in[10];
  const float* mb2 = (const float*)d_in[11];
  const float* nw1 = (const float*)d_in[12];
  const float* nb1 = (const float*)d_in[13];
  const float* nw2 = (const float*)d_in[14];
  const float* nb2 = (const float*)d_in[15];
  const float* cw1 = (const float*)d_in[16];
  const float* cb1 = (const float*)d_in[17];
  const float* cw2 = (const float*)d_in[18];
  const float* cb2 = (const float*)d_in[19];
  const float* t1w = (const float*)d_in[20];
  const float* t1b = (const float*)d_in[21];
  const float* t2w = (const float*)d_in[22];
  const float* t2b = (const float*)d_in[23];

  float* W = (float*)d_ws;
  float* h0     = W;                       // ND
  float* aggM0  = h0 + ND;                 // ND (tf/sim alias here)
  float* ag     = aggM0 + ND;              // 2*ND  (N x 256 hidden sums)
  float* parts  = ag + 2 * ND;             // 5*ND
  float* efp    = parts + 5 * ND;          // 262144*16
  float* Wfold  = efp + 262144l * 16;      // 4096
  float* bfold  = Wfold + 4096;            // 256
  float* vbias  = bfold + 256;             // 256
  int*   deg    = (int*)(vbias + 256);     // 32768
  int*   csr_f  = deg + 32768;             // 262144
  int*   rp_g   = csr_f + 262144;          // 512*65 = 33280
  short* cw1t_h = (short*)(rp_g + 33280);  // 65536 shorts per plane
  short* cw1t_m = cw1t_h + 65536;
  short* cw1t_l = cw1t_m + 65536;
  short* nw1t_h = cw1t_l + 65536;
  short* nw1t_m = nw1t_h + 65536;
  short* nw1t_l = nw1t_m + 65536;
  short* cw2t_h = nw1t_l + 65536;          // 32768 each
  short* cw2t_m = cw2t_h + 32768;
  short* cw2t_l = cw2t_m + 32768;
  short* nw2t_h = cw2t_l + 32768;
  short* nw2t_m = nw2t_h + 32768;
  short* nw2t_l = nw2t_m + 32768;
  short* m1t_h  = nw2t_l + 32768;          // mw1[0:256] -> 65536 each
  short* m1t_m  = m1t_h + 65536;
  short* m1t_l  = m1t_m + 65536;
  short* m2t_h  = m1t_l + 65536;           // mw2 -> 32768 each
  short* m2t_m  = m2t_h + 32768;
  short* m2t_l  = m2t_m + 32768;
  short* chp    = m2t_l + 32768;           // comb planes: 32768*128 shorts each
  short* cmp    = chp + 32768l * 128;
  short* clp    = cmp + 32768l * 128;
  float* tf     = aggM0;                   // 32768*64
  float* sim    = aggM0 + 2097152;         // 256*4096
  float* outp   = (float*)d_out;

  k_prep<<<18, 256, 0, stream>>>(eew, eeb, mw1, mb1, mb2, nw1, Wfold, bfold, vbias);
  k_csr<<<512, 256, 0, stream>>>(from_idx, to_idx, ef, csr_f, rp_g, efp, deg);
  k_wsplit3<<<256, 256, 0, stream>>>(cw1, 256, 256, cw1t_h, cw1t_m, cw1t_l);
  k_wsplit3<<<256, 256, 0, stream>>>(nw1, 256, 256, nw1t_h, nw1t_m, nw1t_l);
  k_wsplit3<<<128, 256, 0, stream>>>(cw2, 128, 256, cw2t_h, cw2t_m, cw2t_l);
  k_wsplit3<<<128, 256, 0, stream>>>(nw2, 128, 256, nw2t_h, nw2t_m, nw2t_l);
  k_wsplit3<<<256, 256, 0, stream>>>(mw1, 256, 256, m1t_h, m1t_m, m1t_l);
  k_wsplit3<<<128, 256, 0, stream>>>(mw2, 128, 256, m2t_h, m2t_m, m2t_l);
  k_node_enc<<<16384, 256, 0, stream>>>(nf, new_w, new_b, h0);

  for (int t = 0; t < 3; ++t) {
    const float* hprev = h0;
    for (int p = 1; p <= 5; ++p) {
      if (t > 0 && p > 1)
        k_mlp2m<256, false, false, true, false><<<1024, 256, 0, stream>>>(
            hprev, nullptr, nullptr, nullptr,
            parts + (long)(p - 1) * ND, nullptr, nullptr, nullptr,
            cw1t_h, cw1t_m, cw1t_l, cb1, nullptr, nullptr,
            cw2t_h, cw2t_m, cw2t_l, cb2, nullptr, chp, cmp, clp);
      else
        k_mlp2m<128, false, false, true, false><<<1024, 256, 0, stream>>>(
            hprev, nullptr, nullptr, nullptr, nullptr, nullptr, nullptr, nullptr,
            cw1t_h, cw1t_m, cw1t_l, cb1, nullptr, nullptr,
            cw2t_h, cw2t_m, cw2t_l, cb2, nullptr, chp, cmp, clp);
      k_edgeb<<<dim3(512, 4), 256, 0, stream>>>(chp, cmp, clp, efp,
                                                m1t_h, m1t_m, m1t_l,
                                                Wfold, bfold, csr_f, rp_g, ag);
      float* hnew = parts + (long)(p - 1) * ND;
      k_mlp2m<256, true, true, false, true><<<1024, 256, 0, stream>>>(
          nullptr, chp, cmp, clp, ag, m2t_h, m2t_m, m2t_l,
          nw1t_h, nw1t_m, nw1t_l, nb1, deg, vbias,
          nw2t_h, nw2t_m, nw2t_l, nb2, hnew, nullptr, nullptr, nullptr);
      hprev = hnew;
    }
    k_tfeat<<<8192, 256, 0, stream>>>(parts + 4 * ND, t1w, t1b, t2w, t2b, tf);
    k_sim<<<256, 256, 0, stream>>>(tf, sim);
    k_sink<<<256, 256, 0, stream>>>(sim, outp);
    if (t < 2) {
      for (int pi = 3; pi >= 0; --pi)
        k_mix<<<256, 256, 0, stream>>>(sim, parts + (long)pi * ND, parts + (long)(pi + 1) * ND);
    }
  }
}

// Round 19
// 5534.989 us; speedup vs baseline: 1.0554x; 1.0548x over previous
//
#include <hip/hip_runtime.h>
#include <hip/hip_bf16.h>

#define NNODES   32768
#define NGROUPS  512
#define EPG      512
#define ND       (32768l*128)

typedef __attribute__((ext_vector_type(4))) float f32x4;
typedef __attribute__((ext_vector_type(8))) short bf16x8;

__device__ __forceinline__ short f2bf(float x) {
  unsigned u = __float_as_uint(x);
  unsigned r = (u + 0x7FFF + ((u >> 16) & 1)) >> 16;   // RNE
  return (short)r;
}
__device__ __forceinline__ float bf2f(short h) {
  return __uint_as_float(((unsigned)(unsigned short)h) << 16);
}
// 3-term bf16 split: x ~= h + m + l  (covers ~24 mantissa bits)
__device__ __forceinline__ void split3(float x, short* ph, short* pm, short* pl, long idx) {
  short h = f2bf(x); float r1 = x - bf2f(h);
  short m = f2bf(r1); float r2 = r1 - bf2f(m);
  ph[idx] = h; pm[idx] = m; pl[idx] = f2bf(r2);
}

// ---------------------------------------------------------------------------
// h0 = node_features(32768x32) @ W(32x128) + b
__global__ void k_node_enc(const float* __restrict__ nf, const float* __restrict__ w,
                           const float* __restrict__ b, float* __restrict__ h0) {
  int idx = blockIdx.x * 256 + threadIdx.x;
  int row = idx >> 7, col = idx & 127;
  const float* x = nf + row * 32;
  float acc = b[col];
#pragma unroll
  for (int k = 0; k < 32; ++k) acc = fmaf(x[k], w[k * 128 + col], acc);
  h0[idx] = acc;
}

// ---------------------------------------------------------------------------
// Folded weights (fp32):
//  blocks 0..15 : Wfold[16][256] = eew(16x64) @ mw1[256:320,:]
//  block  16    : bfold[256]     = eeb @ mw1[256:320,:] + mb1
//  block  17    : vbias[256]     = mb2 @ nw1[128:256,:]
__global__ void k_prep(const float* __restrict__ eew, const float* __restrict__ eeb,
                       const float* __restrict__ mw1, const float* __restrict__ mb1,
                       const float* __restrict__ mb2, const float* __restrict__ nw1,
                       float* __restrict__ Wfold, float* __restrict__ bfold,
                       float* __restrict__ vbias) {
  const int c = threadIdx.x, b = blockIdx.x;
  if (b < 16) {
    float a = 0.f;
    for (int j = 0; j < 64; ++j) a = fmaf(eew[b * 64 + j], mw1[(256 + j) * 256 + c], a);
    Wfold[b * 256 + c] = a;
  } else if (b == 16) {
    float a = mb1[c];
    for (int j = 0; j < 64; ++j) a = fmaf(eeb[j], mw1[(256 + j) * 256 + c], a);
    bfold[c] = a;
  } else {
    float a = 0.f;
    for (int j = 0; j < 128; ++j) a = fmaf(mb2[j], nw1[(128 + j) * 256 + c], a);
    vbias[c] = a;
  }
}

// ---------------------------------------------------------------------------
// Weight transpose + bf16x3 split: W (>=Kd x C row-major) -> Wt[c][k], k-stride 256
__global__ void k_wsplit3(const float* __restrict__ W, int C, int Kd,
                          short* __restrict__ th, short* __restrict__ tm,
                          short* __restrict__ tl) {
  const int c = blockIdx.x;
  for (int k = threadIdx.x; k < Kd; k += 256) {
    float w = W[(long)k * C + c];
    split3(w, th, tm, tl, c * 256 + k);
  }
}

// ---------------------------------------------------------------------------
// Deterministic CSR per group: edges stably sorted by to-node.
__global__ void k_csr(const int* __restrict__ from_idx, const int* __restrict__ to_idx,
                      const float* __restrict__ ef,
                      int* __restrict__ csr_f, int* __restrict__ rp_g,
                      float* __restrict__ efp, int* __restrict__ deg) {
  __shared__ int cnt[64], rps[65];
  __shared__ int tls[EPG], fls[EPG];
  __shared__ short ord[EPG];
  const int g = blockIdx.x, tid = threadIdx.x;
  const int be = g * EPG, bn = g * 64;
  if (tid < 64) cnt[tid] = 0;
  __syncthreads();
  for (int e = tid; e < EPG; e += 256) {
    int t = to_idx[be + e] - bn;
    tls[e] = t;
    fls[e] = from_idx[be + e] - bn;
    atomicAdd(&cnt[t], 1);
  }
  __syncthreads();
  if (tid == 0) {
    int s = 0;
    for (int i = 0; i < 64; ++i) { rps[i] = s; s += cnt[i]; }
    rps[64] = s;
  }
  __syncthreads();
  if (tid < 64) {
    int pos = rps[tid];
    for (int e = 0; e < EPG; ++e)
      if (tls[e] == tid) ord[pos++] = (short)e;
  }
  __syncthreads();
  for (int ec = tid; ec < EPG; ec += 256) {
    const int eo = ord[ec];
    csr_f[be + ec] = fls[eo];
    const float4* src = (const float4*)&ef[(long)(be + eo) * 16];
    float4* dst = (float4*)&efp[(long)(be + ec) * 16];
    dst[0] = src[0]; dst[1] = src[1]; dst[2] = src[2]; dst[3] = src[3];
  }
  if (tid < 65) rp_g[g * 65 + tid] = rps[tid];
  if (tid < 64) deg[bn + tid] = cnt[tid];
}

// ---------------------------------------------------------------------------
// MFMA bf16x3 2-layer MLP. X = [x0 | x1].
// RPX0: x0 read from pre-split planes. WPOUT: output written as bf16x3 planes.
// AGG: x1 is ag (N x 256); a pre-phase computes agg = ag @ mw2 via MFMA
//      (two-chain, bit-identical to the former k_aggm) and stages it as
//      bf16x3 into cols 128..255 of the staging buffer.
template<int KTOT, bool DEG, bool RPX0, bool WPOUT, bool AGG>
__global__ __launch_bounds__(256, 3)
void k_mlp2m(const float* __restrict__ x0,
             const short* __restrict__ x0h, const short* __restrict__ x0m,
             const short* __restrict__ x0l,
             const float* __restrict__ x1,
             const short* __restrict__ A2h, const short* __restrict__ A2m,
             const short* __restrict__ A2l,
             const short* __restrict__ W1h, const short* __restrict__ W1m,
             const short* __restrict__ W1l,
             const float* __restrict__ b1, const int* __restrict__ deg,
             const float* __restrict__ vbias,
             const short* __restrict__ W2h, const short* __restrict__ W2m,
             const short* __restrict__ W2l,
             const float* __restrict__ b2,
             float* __restrict__ out,
             short* __restrict__ outh, short* __restrict__ outm,
             short* __restrict__ outl) {
  __shared__ short xh[32 * 264];
  __shared__ short xm[32 * 264];
  __shared__ short xl[32 * 264];
  __shared__ int degs[32];
  const int tid = threadIdx.x;
  const long row0 = (long)blockIdx.x * 32;

  const int lane = tid & 63, wid = tid >> 6;
  const int lr = lane & 15;
  const int lk = (lane >> 4) * 8;
  const int rsub = (lane >> 4) * 4;

  if constexpr (AGG) {
    // pre-phase: agg(32x128) = ag(32x256) @ mw2, two accumulation chains
    for (int i = tid; i < 2048; i += 256) {
      const int r = i >> 6, q = i & 63;
      float4 v = *(const float4*)&x1[(row0 + r) * 256 + q * 4];
      const int base = r * 264 + q * 4;
      split3(v.x, xh, xm, xl, base + 0);
      split3(v.y, xh, xm, xl, base + 1);
      split3(v.z, xh, xm, xl, base + 2);
      split3(v.w, xh, xm, xl, base + 3);
    }
    __syncthreads();

    f32x4 s0[2][2], s1[2][2];
#pragma unroll
    for (int fc = 0; fc < 2; ++fc)
#pragma unroll
      for (int fr = 0; fr < 2; ++fr) { s0[fr][fc] = {0.f,0.f,0.f,0.f}; s1[fr][fc] = {0.f,0.f,0.f,0.f}; }

#pragma unroll 2
    for (int ks = 0; ks < 4; ++ks) {          // K half 0: 0..127
      const int k0 = ks * 32 + lk;
      bf16x8 ah[2], am[2], al[2];
#pragma unroll
      for (int fr = 0; fr < 2; ++fr) {
        const int ab = (fr * 16 + lr) * 264 + k0;
        ah[fr] = *(const bf16x8*)&xh[ab];
        am[fr] = *(const bf16x8*)&xm[ab];
        al[fr] = *(const bf16x8*)&xl[ab];
      }
#pragma unroll
      for (int fc = 0; fc < 2; ++fc) {
        const long wrow = (long)(wid * 32 + fc * 16 + lr) * 256 + k0;
        const bf16x8 bh = *(const bf16x8*)&A2h[wrow];
        const bf16x8 bm = *(const bf16x8*)&A2m[wrow];
        const bf16x8 bl = *(const bf16x8*)&A2l[wrow];
#pragma unroll
        for (int fr = 0; fr < 2; ++fr) {
          s0[fr][fc] = __builtin_amdgcn_mfma_f32_16x16x32_bf16(ah[fr], bh, s0[fr][fc], 0, 0, 0);
          s0[fr][fc] = __builtin_amdgcn_mfma_f32_16x16x32_bf16(ah[fr], bm, s0[fr][fc], 0, 0, 0);
          s0[fr][fc] = __builtin_amdgcn_mfma_f32_16x16x32_bf16(am[fr], bh, s0[fr][fc], 0, 0, 0);
          s0[fr][fc] = __builtin_amdgcn_mfma_f32_16x16x32_bf16(ah[fr], bl, s0[fr][fc], 0, 0, 0);
          s0[fr][fc] = __builtin_amdgcn_mfma_f32_16x16x32_bf16(am[fr], bm, s0[fr][fc], 0, 0, 0);
          s0[fr][fc] = __builtin_amdgcn_mfma_f32_16x16x32_bf16(al[fr], bh, s0[fr][fc], 0, 0, 0);
        }
      }
    }
#pragma unroll 2
    for (int ks = 4; ks < 8; ++ks) {          // K half 1: 128..255
      const int k0 = ks * 32 + lk;
      bf16x8 ah[2], am[2], al[2];
#pragma unroll
      for (int fr = 0; fr < 2; ++fr) {
        const int ab = (fr * 16 + lr) * 264 + k0;
        ah[fr] = *(const bf16x8*)&xh[ab];
        am[fr] = *(const bf16x8*)&xm[ab];
        al[fr] = *(const bf16x8*)&xl[ab];
      }
#pragma unroll
      for (int fc = 0; fc < 2; ++fc) {
        const long wrow = (long)(wid * 32 + fc * 16 + lr) * 256 + k0;
        const bf16x8 bh = *(const bf16x8*)&A2h[wrow];
        const bf16x8 bm = *(const bf16x8*)&A2m[wrow];
        const bf16x8 bl = *(const bf16x8*)&A2l[wrow];
#pragma unroll
        for (int fr = 0; fr < 2; ++fr) {
          s1[fr][fc] = __builtin_amdgcn_mfma_f32_16x16x32_bf16(ah[fr], bh, s1[fr][fc], 0, 0, 0);
          s1[fr][fc] = __builtin_amdgcn_mfma_f32_16x16x32_bf16(ah[fr], bm, s1[fr][fc], 0, 0, 0);
          s1[fr][fc] = __builtin_amdgcn_mfma_f32_16x16x32_bf16(am[fr], bh, s1[fr][fc], 0, 0, 0);
          s1[fr][fc] = __builtin_amdgcn_mfma_f32_16x16x32_bf16(ah[fr], bl, s1[fr][fc], 0, 0, 0);
          s1[fr][fc] = __builtin_amdgcn_mfma_f32_16x16x32_bf16(am[fr], bm, s1[fr][fc], 0, 0, 0);
          s1[fr][fc] = __builtin_amdgcn_mfma_f32_16x16x32_bf16(al[fr], bh, s1[fr][fc], 0, 0, 0);
        }
      }
    }
    __syncthreads();   // all ag reads done before staging overwrite

    // split3(agg) into cols 128..255 (same value as old global round-trip)
#pragma unroll
    for (int fr = 0; fr < 2; ++fr)
#pragma unroll
      for (int fc = 0; fc < 2; ++fc) {
        const int col = wid * 32 + fc * 16 + lr;
#pragma unroll
        for (int r = 0; r < 4; ++r) {
          const int row = fr * 16 + rsub + r;
          split3(s0[fr][fc][r] + s1[fr][fc][r], xh, xm, xl, row * 264 + 128 + col);
        }
      }
  }

  if constexpr (RPX0) {
    for (int i = tid; i < 32 * 16; i += 256) {
      const int r = i >> 4, q = i & 15;
      const long gb = (row0 + r) * 128 + q * 8;
      const int lb = r * 264 + q * 8;
      *(bf16x8*)&xh[lb] = *(const bf16x8*)&x0h[gb];
      *(bf16x8*)&xm[lb] = *(const bf16x8*)&x0m[gb];
      *(bf16x8*)&xl[lb] = *(const bf16x8*)&x0l[gb];
    }
  } else {
    for (int i = tid; i < 32 * 32; i += 256) {
      const int r = i >> 5, q = i & 31;
      float4 v = *(const float4*)&x0[(row0 + r) * 128 + q * 4];
      const int base = r * 264 + q * 4;
      split3(v.x, xh, xm, xl, base + 0);
      split3(v.y, xh, xm, xl, base + 1);
      split3(v.z, xh, xm, xl, base + 2);
      split3(v.w, xh, xm, xl, base + 3);
    }
  }
  if constexpr (KTOT == 256 && !AGG) {
    for (int i = tid; i < 32 * 32; i += 256) {
      const int r = i >> 5, q = i & 31;
      float4 v = *(const float4*)&x1[(row0 + r) * 128 + q * 4];
      const int base = r * 264 + 128 + q * 4;
      split3(v.x, xh, xm, xl, base + 0);
      split3(v.y, xh, xm, xl, base + 1);
      split3(v.z, xh, xm, xl, base + 2);
      split3(v.w, xh, xm, xl, base + 3);
    }
  }
  if constexpr (DEG) { if (tid < 32) degs[tid] = deg[row0 + tid]; }
  __syncthreads();

  // ---- layer 1: 32 x 256, wave cols [wid*64, wid*64+64) ----
  f32x4 acc[2][4];
#pragma unroll
  for (int fc = 0; fc < 4; ++fc) {
    const int col = wid * 64 + fc * 16 + lr;
    const float bv = b1[col];
#pragma unroll
    for (int fr = 0; fr < 2; ++fr) acc[fr][fc] = {bv, bv, bv, bv};
    if constexpr (DEG) {
      const float vb = vbias[col];
#pragma unroll
      for (int fr = 0; fr < 2; ++fr)
#pragma unroll
        for (int r = 0; r < 4; ++r)
          acc[fr][fc][r] += (float)degs[fr * 16 + rsub + r] * vb;
    }
  }

#pragma unroll 2
  for (int ks = 0; ks < KTOT / 32; ++ks) {
    const int k0 = ks * 32 + lk;
    bf16x8 ah[2], am[2], al[2];
#pragma unroll
    for (int fr = 0; fr < 2; ++fr) {
      const int ab = (fr * 16 + lr) * 264 + k0;
      ah[fr] = *(const bf16x8*)&xh[ab];
      am[fr] = *(const bf16x8*)&xm[ab];
      al[fr] = *(const bf16x8*)&xl[ab];
    }
#pragma unroll
    for (int fc = 0; fc < 4; ++fc) {
      const long wrow = (long)(wid * 64 + fc * 16 + lr) * 256 + k0;
      const bf16x8 bh = *(const bf16x8*)&W1h[wrow];
      const bf16x8 bm = *(const bf16x8*)&W1m[wrow];
      const bf16x8 bl = *(const bf16x8*)&W1l[wrow];
#pragma unroll
      for (int fr = 0; fr < 2; ++fr) {
        acc[fr][fc] = __builtin_amdgcn_mfma_f32_16x16x32_bf16(ah[fr], bh, acc[fr][fc], 0, 0, 0);
        acc[fr][fc] = __builtin_amdgcn_mfma_f32_16x16x32_bf16(ah[fr], bm, acc[fr][fc], 0, 0, 0);
        acc[fr][fc] = __builtin_amdgcn_mfma_f32_16x16x32_bf16(am[fr], bh, acc[fr][fc], 0, 0, 0);
        acc[fr][fc] = __builtin_amdgcn_mfma_f32_16x16x32_bf16(ah[fr], bl, acc[fr][fc], 0, 0, 0);
        acc[fr][fc] = __builtin_amdgcn_mfma_f32_16x16x32_bf16(am[fr], bm, acc[fr][fc], 0, 0, 0);
        acc[fr][fc] = __builtin_amdgcn_mfma_f32_16x16x32_bf16(al[fr], bh, acc[fr][fc], 0, 0, 0);
      }
    }
  }
  __syncthreads();

  // relu + split3 + store hidden to LDS [row][hcol]
#pragma unroll
  for (int fr = 0; fr < 2; ++fr)
#pragma unroll
    for (int fc = 0; fc < 4; ++fc) {
      const int col = wid * 64 + fc * 16 + lr;
#pragma unroll
      for (int r = 0; r < 4; ++r) {
        const int row = fr * 16 + rsub + r;
        float v = fmaxf(acc[fr][fc][r], 0.f);
        split3(v, xh, xm, xl, row * 264 + col);
      }
    }
  __syncthreads();

  // ---- layer 2: 32 x 128, wave cols [wid*32, wid*32+32) ----
  f32x4 acc2[2][2];
#pragma unroll
  for (int fc = 0; fc < 2; ++fc) {
    const float bv = b2[wid * 32 + fc * 16 + lr];
#pragma unroll
    for (int fr = 0; fr < 2; ++fr) acc2[fr][fc] = {bv, bv, bv, bv};
  }
#pragma unroll 2
  for (int ks = 0; ks < 8; ++ks) {
    const int k0 = ks * 32 + lk;
    bf16x8 ah[2], am[2], al[2];
#pragma unroll
    for (int fr = 0; fr < 2; ++fr) {
      const int ab = (fr * 16 + lr) * 264 + k0;
      ah[fr] = *(const bf16x8*)&xh[ab];
      am[fr] = *(const bf16x8*)&xm[ab];
      al[fr] = *(const bf16x8*)&xl[ab];
    }
#pragma unroll
    for (int fc = 0; fc < 2; ++fc) {
      const long wrow = (long)(wid * 32 + fc * 16 + lr) * 256 + k0;
      const bf16x8 bh = *(const bf16x8*)&W2h[wrow];
      const bf16x8 bm = *(const bf16x8*)&W2m[wrow];
      const bf16x8 bl = *(const bf16x8*)&W2l[wrow];
#pragma unroll
      for (int fr = 0; fr < 2; ++fr) {
        acc2[fr][fc] = __builtin_amdgcn_mfma_f32_16x16x32_bf16(ah[fr], bh, acc2[fr][fc], 0, 0, 0);
        acc2[fr][fc] = __builtin_amdgcn_mfma_f32_16x16x32_bf16(ah[fr], bm, acc2[fr][fc], 0, 0, 0);
        acc2[fr][fc] = __builtin_amdgcn_mfma_f32_16x16x32_bf16(am[fr], bh, acc2[fr][fc], 0, 0, 0);
        acc2[fr][fc] = __builtin_amdgcn_mfma_f32_16x16x32_bf16(ah[fr], bl, acc2[fr][fc], 0, 0, 0);
        acc2[fr][fc] = __builtin_amdgcn_mfma_f32_16x16x32_bf16(am[fr], bm, acc2[fr][fc], 0, 0, 0);
        acc2[fr][fc] = __builtin_amdgcn_mfma_f32_16x16x32_bf16(al[fr], bh, acc2[fr][fc], 0, 0, 0);
      }
    }
  }
#pragma unroll
  for (int fr = 0; fr < 2; ++fr)
#pragma unroll
    for (int fc = 0; fc < 2; ++fc) {
      const int col = wid * 32 + fc * 16 + lr;
#pragma unroll
      for (int r = 0; r < 4; ++r) {
        const long gi = (row0 + fr * 16 + rsub + r) * 128 + col;
        if constexpr (WPOUT) {
          split3(acc2[fr][fc][r], outh, outm, outl, gi);
        } else {
          out[gi] = acc2[fr][fc][r];
        }
      }
    }
}

// ---------------------------------------------------------------------------
// Edge kernel, phases a+b. grid (4, 512): blockIdx.x = col-block, blockIdx.y =
// group, so the 4 col-blocks of one group are dispatch-adjacent and share the
// group's comb-plane rows + efp slice in L2 (pure index remap, no math change).
// phase a: cA/cB = comb_planes @ mw1t[cb] (MFMA) -> LDS.
// phase b: CSR edge loop (3-edge ILP) -> hidden-sum written to global ag (N x 256).
__global__ __launch_bounds__(256, 3)
void k_edgeb(const short* __restrict__ chp, const short* __restrict__ cmp,
             const short* __restrict__ clp,
             const float* __restrict__ efp,
             const short* __restrict__ m1h, const short* __restrict__ m1m,
             const short* __restrict__ m1l,
             const float* __restrict__ Wfold, const float* __restrict__ bfold,
             const int* __restrict__ csr_f, const int* __restrict__ rp_g,
             float* __restrict__ ag) {
  __shared__ __align__(16) float cAB[2 * 64 * 68];   // cA | cB
  __shared__ short fl[EPG];
  __shared__ int rp[65];
  float* cA = cAB;
  float* cB = cAB + 64 * 68;

  const int tid = threadIdx.x;
  const int cb = blockIdx.x, g = blockIdx.y;
  const int be = g * EPG, bn = g * 64;
  const int col0 = cb * 64;

  for (int i = tid; i < EPG; i += 256) fl[i] = (short)csr_f[be + i];
  if (tid < 65) rp[tid] = rp_g[g * 65 + tid];

  const int lane = tid & 63, wid = tid >> 6;
  const int lr = lane & 15;
  const int lk = (lane >> 4) * 8;
  const int rsub = (lane >> 4) * 4;
  const int ng = tid >> 4, cg = tid & 15;
  const int n0 = ng * 4, cq = cg * 4;

  // phase a: waves 0,1 -> cA (mw1 k 0..127); waves 2,3 -> cB (k 128..255).
  {
    const int isB = wid >> 1;
    const int cw = (wid & 1) * 32;
    const int wkof = isB * 128;
    float* dstC = isB ? cB : cA;
#pragma unroll 1
    for (int hf = 0; hf < 2; ++hf) {
      f32x4 c[2][2];
#pragma unroll
      for (int fr = 0; fr < 2; ++fr)
#pragma unroll
        for (int fc = 0; fc < 2; ++fc) c[fr][fc] = {0.f, 0.f, 0.f, 0.f};
      for (int ks = 0; ks < 4; ++ks) {
        const int k0 = ks * 32 + lk;
        bf16x8 ah[2], am[2], al[2];
#pragma unroll
        for (int fr = 0; fr < 2; ++fr) {
          const long ga = (long)(bn + (hf * 2 + fr) * 16 + lr) * 128 + k0;
          ah[fr] = *(const bf16x8*)&chp[ga];
          am[fr] = *(const bf16x8*)&cmp[ga];
          al[fr] = *(const bf16x8*)&clp[ga];
        }
#pragma unroll
        for (int fc = 0; fc < 2; ++fc) {
          const long wrow = (long)(col0 + cw + fc * 16 + lr) * 256 + wkof + k0;
          const bf16x8 bh = *(const bf16x8*)&m1h[wrow];
          const bf16x8 bm = *(const bf16x8*)&m1m[wrow];
          const bf16x8 bl = *(const bf16x8*)&m1l[wrow];
#pragma unroll
          for (int fr = 0; fr < 2; ++fr) {
            c[fr][fc] = __builtin_amdgcn_mfma_f32_16x16x32_bf16(ah[fr], bh, c[fr][fc], 0, 0, 0);
            c[fr][fc] = __builtin_amdgcn_mfma_f32_16x16x32_bf16(ah[fr], bm, c[fr][fc], 0, 0, 0);
            c[fr][fc] = __builtin_amdgcn_mfma_f32_16x16x32_bf16(am[fr], bh, c[fr][fc], 0, 0, 0);
            c[fr][fc] = __builtin_amdgcn_mfma_f32_16x16x32_bf16(ah[fr], bl, c[fr][fc], 0, 0, 0);
            c[fr][fc] = __builtin_amdgcn_mfma_f32_16x16x32_bf16(am[fr], bm, c[fr][fc], 0, 0, 0);
            c[fr][fc] = __builtin_amdgcn_mfma_f32_16x16x32_bf16(al[fr], bh, c[fr][fc], 0, 0, 0);
          }
        }
      }
#pragma unroll
      for (int fr = 0; fr < 2; ++fr)
#pragma unroll
        for (int fc = 0; fc < 2; ++fc) {
          const int col = cw + fc * 16 + lr;
#pragma unroll
          for (int r = 0; r < 4; ++r)
            dstC[((hf * 2 + fr) * 16 + rsub + r) * 68 + col] = c[fr][fc][r];
        }
    }
  }
  float4 Wf[16];
#pragma unroll
  for (int k = 0; k < 16; ++k) Wf[k] = *(const float4*)&Wfold[k * 256 + col0 + cq];
  const float4 bf = *(const float4*)&bfold[col0 + cq];
  __syncthreads();   // cA/cB + fl/rp visible

  // phase b: edge phase (fp32 CSR, atomic-free, 3-edge ILP) -> global ag
#pragma unroll
  for (int i = 0; i < 4; ++i) {
    const int n = n0 + i;
    const float4 cBn = *(const float4*)&cB[n * 68 + cq];
    const int eEnd = rp[n + 1];
    float4 a0 = make_float4(0.f, 0.f, 0.f, 0.f);
    float4 a1 = make_float4(0.f, 0.f, 0.f, 0.f);
    float4 a2 = make_float4(0.f, 0.f, 0.f, 0.f);
    int e = rp[n];
    for (; e + 2 < eEnd; e += 3) {
      const int f0 = fl[e], f1 = fl[e + 1], f2 = fl[e + 2];
      const float* er0 = efp + (long)(be + e) * 16;
      const float* er1 = efp + (long)(be + e + 1) * 16;
      const float* er2 = efp + (long)(be + e + 2) * 16;
      float4 ea[4], eb[4], ec[4];
#pragma unroll
      for (int kq = 0; kq < 4; ++kq) {
        ea[kq] = ((const float4*)er0)[kq];
        eb[kq] = ((const float4*)er1)[kq];
        ec[kq] = ((const float4*)er2)[kq];
      }
      float4 h0 = bf, h1 = bf, h2 = bf;
#pragma unroll
      for (int kq = 0; kq < 4; ++kq) {
        const float ev0[4] = {ea[kq].x, ea[kq].y, ea[kq].z, ea[kq].w};
        const float ev1[4] = {eb[kq].x, eb[kq].y, eb[kq].z, eb[kq].w};
        const float ev2[4] = {ec[kq].x, ec[kq].y, ec[kq].z, ec[kq].w};
#pragma unroll
        for (int s = 0; s < 4; ++s) {
          const float4 w = Wf[kq * 4 + s];
          h0.x = fmaf(ev0[s], w.x, h0.x); h0.y = fmaf(ev0[s], w.y, h0.y);
          h0.z = fmaf(ev0[s], w.z, h0.z); h0.w = fmaf(ev0[s], w.w, h0.w);
          h1.x = fmaf(ev1[s], w.x, h1.x); h1.y = fmaf(ev1[s], w.y, h1.y);
          h1.z = fmaf(ev1[s], w.z, h1.z); h1.w = fmaf(ev1[s], w.w, h1.w);
          h2.x = fmaf(ev2[s], w.x, h2.x); h2.y = fmaf(ev2[s], w.y, h2.y);
          h2.z = fmaf(ev2[s], w.z, h2.z); h2.w = fmaf(ev2[s], w.w, h2.w);
        }
      }
      const float4 va0 = *(const float4*)&cA[f0 * 68 + cq];
      const float4 va1 = *(const float4*)&cA[f1 * 68 + cq];
      const float4 va2 = *(const float4*)&cA[f2 * 68 + cq];
      a0.x += fmaxf(h0.x + va0.x + cBn.x, 0.f);
      a0.y += fmaxf(h0.y + va0.y + cBn.y, 0.f);
      a0.z += fmaxf(h0.z + va0.z + cBn.z, 0.f);
      a0.w += fmaxf(h0.w + va0.w + cBn.w, 0.f);
      a1.x += fmaxf(h1.x + va1.x + cBn.x, 0.f);
      a1.y += fmaxf(h1.y + va1.y + cBn.y, 0.f);
      a1.z += fmaxf(h1.z + va1.z + cBn.z, 0.f);
      a1.w += fmaxf(h1.w + va1.w + cBn.w, 0.f);
      a2.x += fmaxf(h2.x + va2.x + cBn.x, 0.f);
      a2.y += fmaxf(h2.y + va2.y + cBn.y, 0.f);
      a2.z += fmaxf(h2.z + va2.z + cBn.z, 0.f);
      a2.w += fmaxf(h2.w + va2.w + cBn.w, 0.f);
    }
    for (; e < eEnd; ++e) {   // tail (0..2 edges)
      const int f = fl[e];
      const float* er = efp + (long)(be + e) * 16;
      float4 h = bf;
#pragma unroll
      for (int kq = 0; kq < 4; ++kq) {
        const float4 e4 = ((const float4*)er)[kq];
        const float ev[4] = {e4.x, e4.y, e4.z, e4.w};
#pragma unroll
        for (int s = 0; s < 4; ++s) {
          const float4 w = Wf[kq * 4 + s];
          h.x = fmaf(ev[s], w.x, h.x); h.y = fmaf(ev[s], w.y, h.y);
          h.z = fmaf(ev[s], w.z, h.z); h.w = fmaf(ev[s], w.w, h.w);
        }
      }
      const float4 va = *(const float4*)&cA[f * 68 + cq];
      a0.x += fmaxf(h.x + va.x + cBn.x, 0.f);
      a0.y += fmaxf(h.y + va.y + cBn.y, 0.f);
      a0.z += fmaxf(h.z + va.z + cBn.z, 0.f);
      a0.w += fmaxf(h.w + va.w + cBn.w, 0.f);
    }
    a0.x += a1.x; a0.y += a1.y; a0.z += a1.z; a0.w += a1.w;
    a0.x += a2.x; a0.y += a2.y; a0.z += a2.z; a0.w += a2.w;
    *(float4*)&ag[(long)(bn + n) * 256 + col0 + cq] = a0;
  }
}

// ---------------------------------------------------------------------------
__global__ void k_tfeat(const float* __restrict__ x,
                        const float* __restrict__ t1w, const float* __restrict__ t1b,
                        const float* __restrict__ t2w, const float* __restrict__ t2b,
                        float* __restrict__ tf) {
  __shared__ float xs[4][128];
  __shared__ float ys[4][64];
  const int tid = threadIdx.x;
  const long row0 = (long)blockIdx.x * 4;
  for (int i = tid; i < 512; i += 256)
    xs[i >> 7][i & 127] = x[(row0 + (i >> 7)) * 128 + (i & 127)];
  __syncthreads();
  const int r = tid >> 6, c = tid & 63;
  float acc = t1b[c];
#pragma unroll 4
  for (int k = 0; k < 128; ++k) acc = fmaf(xs[r][k], t1w[k * 64 + c], acc);
  ys[r][c] = fmaxf(acc, 0.f);
  __syncthreads();
  float a2 = t2b[c];
#pragma unroll 4
  for (int k = 0; k < 64; ++k) a2 = fmaf(ys[r][k], t2w[k * 64 + c], a2);
  tf[(row0 + r) * 64 + c] = a2;
}

// ---------------------------------------------------------------------------
__global__ void k_sim(const float* __restrict__ tf, float* __restrict__ sim) {
  const int b = blockIdx.x, tid = threadIdx.x;
  __shared__ float tq[64][65];
  __shared__ float tcs[64][65];
  for (int i = tid; i < 4096; i += 256) {
    tq[i >> 6][i & 63]  = tf[(long)b * 8192 + i];
    tcs[i >> 6][i & 63] = tf[(long)b * 8192 + 4096 + i];
  }
  __syncthreads();
  const int m = tid >> 2, j0 = (tid & 3) * 16;
#pragma unroll
  for (int j = 0; j < 16; ++j) {
    float a = 0.f;
#pragma unroll 4
    for (int k = 0; k < 64; ++k) a = fmaf(tq[m][k], tcs[j0 + j][k], a);
    sim[(long)b * 4096 + m * 64 + j0 + j] = a;
  }
}

// ---------------------------------------------------------------------------
__global__ void k_sink(float* __restrict__ sim, float* __restrict__ outp) {
  const int b = blockIdx.x, tid = threadIdx.x;
  __shared__ float la[64][65];
  const float C = 14.426950408889634f;   // 10 / ln(2)
  for (int i = tid; i < 4096; i += 256)
    la[i >> 6][i & 63] = sim[(long)b * 4096 + i] * C;
  __syncthreads();
  const int r4 = tid >> 2, l4 = tid & 3;
  for (int it = 0; it < 20; ++it) {
    {
      float m = -3.4e38f;
#pragma unroll
      for (int i = 0; i < 16; ++i) m = fmaxf(m, la[r4][l4 + 4 * i]);
      m = fmaxf(m, __shfl_xor(m, 1)); m = fmaxf(m, __shfl_xor(m, 2));
      float s = 0.f;
#pragma unroll
      for (int i = 0; i < 16; ++i) s += exp2f(la[r4][l4 + 4 * i] - m);
      s += __shfl_xor(s, 1); s += __shfl_xor(s, 2);
      const float lse = m + log2f(s);
#pragma unroll
      for (int i = 0; i < 16; ++i) la[r4][l4 + 4 * i] -= lse;
    }
    __syncthreads();
    {
      float m = -3.4e38f;
#pragma unroll
      for (int i = 0; i < 16; ++i) m = fmaxf(m, la[l4 + 4 * i][r4]);
      m = fmaxf(m, __shfl_xor(m, 1)); m = fmaxf(m, __shfl_xor(m, 2));
      float s = 0.f;
#pragma unroll
      for (int i = 0; i < 16; ++i) s += exp2f(la[l4 + 4 * i][r4] - m);
      s += __shfl_xor(s, 1); s += __shfl_xor(s, 2);
      const float lse = m + log2f(s);
#pragma unroll
      for (int i = 0; i < 16; ++i) la[l4 + 4 * i][r4] -= lse;
    }
    __syncthreads();
  }
  for (int i = tid; i < 4096; i += 256) {
    const float v = exp2f(la[i >> 6][i & 63]);
    outp[(long)b * 4096 + i] = v;
    sim[(long)b * 4096 + i] = v;
  }
}

// ---------------------------------------------------------------------------
__global__ void k_mix(const float* __restrict__ plan, const float* __restrict__ src,
                      float* __restrict__ dst) {
  const int b = blockIdx.x, tid = threadIdx.x;
  __shared__ float pl[64][65];
  __shared__ float qs[64][128];
  __shared__ float cs[64][128];
  const long qbase = (long)(2 * b) * 64, cbase = qbase + 64;
  for (int i = tid; i < 4096; i += 256) pl[i >> 6][i & 63] = plan[(long)b * 4096 + i];
  for (int i = tid; i < 8192; i += 256) {
    qs[i >> 7][i & 127] = src[qbase * 128 + i];
    cs[i >> 7][i & 127] = src[cbase * 128 + i];
  }
  __syncthreads();
  const int d = tid & 127, m0 = (tid >> 7) * 32;
  for (int m = m0; m < m0 + 32; ++m) {
    float a = 0.f;
#pragma unroll 4
    for (int j = 0; j < 64; ++j) a = fmaf(pl[m][j], cs[j][d], a);
    dst[(qbase + m) * 128 + d] = a;
  }
  for (int j = m0; j < m0 + 32; ++j) {
    float a = 0.f;
#pragma unroll 4
    for (int m = 0; m < 64; ++m) a = fmaf(pl[m][j], qs[m][d], a);
    dst[(cbase + j) * 128 + d] = a;
  }
}

// ---------------------------------------------------------------------------
extern "C" void kernel_launch(void* const* d_in, const int* in_sizes, int n_in,
                              void* d_out, int out_size, void* d_ws, size_t ws_size,
                              hipStream_t stream) {
  const float* nf  = (const float*)d_in[0];
  const float* ef  = (const float*)d_in[1];
  const int* from_idx = (const int*)d_in[2];
  const int* to_idx   = (const int*)d_in[3];
  const float* new_w = (const float*)d_in[4];
  const float* new_b = (const float*)d_in[5];
  const float* eew = (const float*)d_in[6];
  const float* eeb = (const float*)d_in[7];
  const float* mw1 = (const float*)d_in[8];
  const float* mb1 = (const float*)d_in[9];
  const float* mw2 = (const float*)d_in[10];
  const float* mb2 = (const float*)d_in[11];
  const float* nw1 = (const float*)d_in[12];
  const float* nb1 = (const float*)d_in[13];
  const float* nw2 = (const float*)d_in[14];
  const float* nb2 = (const float*)d_in[15];
  const float* cw1 = (const float*)d_in[16];
  const float* cb1 = (const float*)d_in[17];
  const float* cw2 = (const float*)d_in[18];
  const float* cb2 = (const float*)d_in[19];
  const float* t1w = (const float*)d_in[20];
  const float* t1b = (const float*)d_in[21];
  const float* t2w = (const float*)d_in[22];
  const float* t2b = (const float*)d_in[23];

  float* W = (float*)d_ws;
  float* h0     = W;                       // ND
  float* aggM0  = h0 + ND;                 // ND (tf/sim alias here)
  float* ag     = aggM0 + ND;              // 2*ND  (N x 256 hidden sums)
  float* parts  = ag + 2 * ND;             // 5*ND
  float* efp    = parts + 5 * ND;          // 262144*16
  float* Wfold  = efp + 262144l * 16;      // 4096
  float* bfold  = Wfold + 4096;            // 256
  float* vbias  = bfold + 256;             // 256
  int*   deg    = (int*)(vbias + 256);     // 32768
  int*   csr_f  = deg + 32768;             // 262144
  int*   rp_g   = csr_f + 262144;          // 512*65 = 33280
  short* cw1t_h = (short*)(rp_g + 33280);  // 65536 shorts per plane
  short* cw1t_m = cw1t_h + 65536;
  short* cw1t_l = cw1t_m + 65536;
  short* nw1t_h = cw1t_l + 65536;
  short* nw1t_m = nw1t_h + 65536;
  short* nw1t_l = nw1t_m + 65536;
  short* cw2t_h = nw1t_l + 65536;          // 32768 each
  short* cw2t_m = cw2t_h + 32768;
  short* cw2t_l = cw2t_m + 32768;
  short* nw2t_h = cw2t_l + 32768;
  short* nw2t_m = nw2t_h + 32768;
  short* nw2t_l = nw2t_m + 32768;
  short* m1t_h  = nw2t_l + 32768;          // mw1[0:256] -> 65536 each
  short* m1t_m  = m1t_h + 65536;
  short* m1t_l  = m1t_m + 65536;
  short* m2t_h  = m1t_l + 65536;           // mw2 -> 32768 each
  short* m2t_m  = m2t_h + 32768;
  short* m2t_l  = m2t_m + 32768;
  short* chp    = m2t_l + 32768;           // comb planes: 32768*128 shorts each
  short* cmp    = chp + 32768l * 128;
  short* clp    = cmp + 32768l * 128;
  float* tf     = aggM0;                   // 32768*64
  float* sim    = aggM0 + 2097152;         // 256*4096
  float* outp   = (float*)d_out;

  k_prep<<<18, 256, 0, stream>>>(eew, eeb, mw1, mb1, mb2, nw1, Wfold, bfold, vbias);
  k_csr<<<512, 256, 0, stream>>>(from_idx, to_idx, ef, csr_f, rp_g, efp, deg);
  k_wsplit3<<<256, 256, 0, stream>>>(cw1, 256, 256, cw1t_h, cw1t_m, cw1t_l);
  k_wsplit3<<<256, 256, 0, stream>>>(nw1, 256, 256, nw1t_h, nw1t_m, nw1t_l);
  k_wsplit3<<<128, 256, 0, stream>>>(cw2, 128, 256, cw2t_h, cw2t_m, cw2t_l);
  k_wsplit3<<<128, 256, 0, stream>>>(nw2, 128, 256, nw2t_h, nw2t_m, nw2t_l);
  k_wsplit3<<<256, 256, 0, stream>>>(mw1, 256, 256, m1t_h, m1t_m, m1t_l);
  k_wsplit3<<<128, 256, 0, stream>>>(mw2, 128, 256, m2t_h, m2t_m, m2t_l);
  k_node_enc<<<16384, 256, 0, stream>>>(nf, new_w, new_b, h0);

  for (int t = 0; t < 3; ++t) {
    const float* hprev = h0;
    for (int p = 1; p <= 5; ++p) {
      if (t > 0 && p > 1)
        k_mlp2m<256, false, false, true, false><<<1024, 256, 0, stream>>>(
            hprev, nullptr, nullptr, nullptr,
            parts + (long)(p - 1) * ND, nullptr, nullptr, nullptr,
            cw1t_h, cw1t_m, cw1t_l, cb1, nullptr, nullptr,
            cw2t_h, cw2t_m, cw2t_l, cb2, nullptr, chp, cmp, clp);
      else
        k_mlp2m<128, false, false, true, false><<<1024, 256, 0, stream>>>(
            hprev, nullptr, nullptr, nullptr, nullptr, nullptr, nullptr, nullptr,
            cw1t_h, cw1t_m, cw1t_l, cb1, nullptr, nullptr,
            cw2t_h, cw2t_m, cw2t_l, cb2, nullptr, chp, cmp, clp);
      k_edgeb<<<dim3(4, 512), 256, 0, stream>>>(chp, cmp, clp, efp,
                                                m1t_h, m1t_m, m1t_l,
                                                Wfold, bfold, csr_f, rp_g, ag);
      float* hnew = parts + (long)(p - 1) * ND;
      k_mlp2m<256, true, true, false, true><<<1024, 256, 0, stream>>>(
          nullptr, chp, cmp, clp, ag, m2t_h, m2t_m, m2t_l,
          nw1t_h, nw1t_m, nw1t_l, nb1, deg, vbias,
          nw2t_h, nw2t_m, nw2t_l, nb2, hnew, nullptr, nullptr, nullptr);
      hprev = hnew;
    }
    k_tfeat<<<8192, 256, 0, stream>>>(parts + 4 * ND, t1w, t1b, t2w, t2b, tf);
    k_sim<<<256, 256, 0, stream>>>(tf, sim);
    k_sink<<<256, 256, 0, stream>>>(sim, outp);
    if (t < 2) {
      for (int pi = 3; pi >= 0; --pi)
        k_mix<<<256, 256, 0, stream>>>(sim, parts + (long)pi * ND, parts + (long)(pi + 1) * ND);
    }
  }
}